// Round 1
// baseline (1119.430 us; speedup 1.0000x reference)
//
#include <hip/hip_runtime.h>
#include <math.h>

#define N_NODES 50000
#define N_EDGES 800000
#define EP (N_EDGES + N_NODES)   // edges + self loops
#define G_GRAPHS 512
#define HID 256
#define HEADS 8
#define NEG_SLOPE 0.2f
#define BN_EPS 1e-5f

// ---------------- CSR build ----------------

__global__ void hist_kernel(const int* __restrict__ ei, int* __restrict__ fill) {
    int e = blockIdx.x * 256 + threadIdx.x;
    if (e >= EP) return;
    int d = (e < N_EDGES) ? ei[N_EDGES + e] : (e - N_EDGES);
    atomicAdd(&fill[d], 1);
}

// single-block exclusive scan of fill[N] -> rowptr[N+1]; also fill[i]=excl
__global__ void scan_kernel(int* __restrict__ fill, int* __restrict__ rowptr) {
    __shared__ int sdata[1024];
    int tid = threadIdx.x;
    int carry = 0;
    const int NCH = (N_NODES + 1023) / 1024;
    for (int ch = 0; ch < NCH; ch++) {
        int idx = ch * 1024 + tid;
        int v = (idx < N_NODES) ? fill[idx] : 0;
        sdata[tid] = v;
        __syncthreads();
        for (int off = 1; off < 1024; off <<= 1) {
            int x = 0;
            if (tid >= off) x = sdata[tid - off];
            __syncthreads();
            sdata[tid] += x;
            __syncthreads();
        }
        int excl = carry + sdata[tid] - v;
        if (idx < N_NODES) { rowptr[idx] = excl; fill[idx] = excl; }
        carry += sdata[1023];
        __syncthreads();
    }
    if (tid == 0) rowptr[N_NODES] = carry;
}

__global__ void scatter_kernel(const int* __restrict__ ei, int* __restrict__ fill,
                               int* __restrict__ esrc) {
    int e = blockIdx.x * 256 + threadIdx.x;
    if (e >= EP) return;
    int s, d;
    if (e < N_EDGES) { s = ei[e]; d = ei[N_EDGES + e]; }
    else             { s = d = e - N_EDGES; }
    int pos = atomicAdd(&fill[d], 1);
    esrc[pos] = s;
}

__global__ void gstart_kernel(const int* __restrict__ batch, int* __restrict__ gstart) {
    int g = blockIdx.x * 64 + threadIdx.x;
    if (g > G_GRAPHS) return;
    int lo = 0, hi = N_NODES;
    while (lo < hi) { int mid = (lo + hi) >> 1; if (batch[mid] < g) lo = mid + 1; else hi = mid; }
    gstart[g] = lo;
}

// ---------------- GEMM: C[N,256] = A[N,K] @ W[K,256] ----------------
// 64x64 tile, BK=16, 256 threads, 4x4 per thread
__global__ __launch_bounds__(256) void gemm_kernel(const float* __restrict__ A,
                                                   const float* __restrict__ W,
                                                   float* __restrict__ C,
                                                   int Nrows, int K) {
    __shared__ float As[16][65];
    __shared__ float Bs[16][64];
    int t = threadIdx.x;
    int tx = t & 15, ty = t >> 4;
    int bm = blockIdx.x * 64, bn = blockIdx.y * 64;
    float c[4][4] = {};
    int arow = t >> 2, aq = t & 3;     // A stage: 64 rows x 16 k
    int brow = t >> 4, bq = t & 15;    // B stage: 16 k x 64 cols
    for (int k0 = 0; k0 < K; k0 += 16) {
        float4 av = {0.f, 0.f, 0.f, 0.f};
        int gr = bm + arow;
        if (gr < Nrows) av = *(const float4*)&A[(size_t)gr * K + k0 + aq * 4];
        As[aq * 4 + 0][arow] = av.x;
        As[aq * 4 + 1][arow] = av.y;
        As[aq * 4 + 2][arow] = av.z;
        As[aq * 4 + 3][arow] = av.w;
        float4 bv = *(const float4*)&W[(size_t)(k0 + brow) * HID + bn + bq * 4];
        *(float4*)&Bs[brow][bq * 4] = bv;
        __syncthreads();
#pragma unroll
        for (int k = 0; k < 16; k++) {
            float4 b = *(float4*)&Bs[k][tx * 4];
#pragma unroll
            for (int i = 0; i < 4; i++) {
                float a = As[k][ty * 4 + i];
                c[i][0] += a * b.x; c[i][1] += a * b.y;
                c[i][2] += a * b.z; c[i][3] += a * b.w;
            }
        }
        __syncthreads();
    }
#pragma unroll
    for (int i = 0; i < 4; i++) {
        int gr = bm + ty * 4 + i;
        if (gr < Nrows) {
            float4 v = {c[i][0], c[i][1], c[i][2], c[i][3]};
            *(float4*)&C[(size_t)gr * HID + bn + tx * 4] = v;
        }
    }
}

// ---------------- attention scores s_src/s_dst [N,8] ----------------
__global__ void score_kernel(const float* __restrict__ hfeat,
                             const float* __restrict__ asrc,
                             const float* __restrict__ adst,
                             float* __restrict__ ssrc, float* __restrict__ sdst) {
    int idx = blockIdx.x * 256 + threadIdx.x;
    if (idx >= N_NODES * HEADS) return;
    int n = idx >> 3, h = idx & 7;
    const float* hp = &hfeat[(size_t)n * HID + h * 32];
    const float* ap = &asrc[h * 32];
    const float* dp = &adst[h * 32];
    float s1 = 0.f, s2 = 0.f;
#pragma unroll
    for (int j = 0; j < 32; j++) {
        float v = hp[j];
        s1 += v * ap[j];
        s2 += v * dp[j];
    }
    ssrc[idx] = s1;
    sdst[idx] = s2;
}

// ---------------- aggregation: one wave per node ----------------
__global__ __launch_bounds__(256) void agg_kernel(
    const float* __restrict__ hfeat, const float* __restrict__ ssrc,
    const float* __restrict__ sdst, const int* __restrict__ rowptr,
    const int* __restrict__ esrc, const float* __restrict__ bias,
    const float* __restrict__ gam, const float* __restrict__ bet,
    const float* __restrict__ bmean, const float* __restrict__ bvar,
    const float* __restrict__ resid, float* __restrict__ outh) {
    int wid = threadIdx.x >> 6;
    int lane = threadIdx.x & 63;
    int n = blockIdx.x * 4 + wid;
    if (n >= N_NODES) return;
    int start = rowptr[n], end = rowptr[n + 1];
    int head = lane >> 3;

    float sd[8];
    {
        float4 t0 = *(const float4*)&sdst[(size_t)n * 8];
        float4 t1 = *(const float4*)&sdst[(size_t)n * 8 + 4];
        sd[0] = t0.x; sd[1] = t0.y; sd[2] = t0.z; sd[3] = t0.w;
        sd[4] = t1.x; sd[5] = t1.y; sd[6] = t1.z; sd[7] = t1.w;
    }

    // phase 1: per-head max over incoming edges
    float lmax[8];
#pragma unroll
    for (int h = 0; h < 8; h++) lmax[h] = -INFINITY;
    for (int i = start + lane; i < end; i += 64) {
        int s = esrc[i];
        float4 t0 = *(const float4*)&ssrc[(size_t)s * 8];
        float4 t1 = *(const float4*)&ssrc[(size_t)s * 8 + 4];
        float sv[8] = {t0.x, t0.y, t0.z, t0.w, t1.x, t1.y, t1.z, t1.w};
#pragma unroll
        for (int h = 0; h < 8; h++) {
            float a = sv[h] + sd[h];
            a = (a >= 0.f) ? a : NEG_SLOPE * a;
            lmax[h] = fmaxf(lmax[h], a);
        }
    }
#pragma unroll
    for (int off = 32; off; off >>= 1) {
#pragma unroll
        for (int h = 0; h < 8; h++)
            lmax[h] = fmaxf(lmax[h], __shfl_xor(lmax[h], off, 64));
    }
    float mxh = lmax[head];
    float sdh = sd[head];

    // phase 2: exp-weighted message accumulation (serial over edges, wave-wide)
    float z = 0.f;
    float4 acc = {0.f, 0.f, 0.f, 0.f};
    for (int i = start; i < end; i++) {
        int s = esrc[i];
        float a = ssrc[(size_t)s * 8 + head] + sdh;
        a = (a >= 0.f) ? a : NEG_SLOPE * a;
        float e = expf(a - mxh);
        z += e;
        float4 hv = *(const float4*)&hfeat[(size_t)s * HID + lane * 4];
        acc.x += e * hv.x; acc.y += e * hv.y;
        acc.z += e * hv.z; acc.w += e * hv.w;
    }
    float inv = 1.f / (z + 1e-16f);
    int c0 = lane * 4;
    float4 bv = *(const float4*)&bias[c0];
    float4 gv = *(const float4*)&gam[c0];
    float4 bev = *(const float4*)&bet[c0];
    float4 mv = *(const float4*)&bmean[c0];
    float4 vv = *(const float4*)&bvar[c0];
    float vals[4] = {acc.x * inv + bv.x, acc.y * inv + bv.y,
                     acc.z * inv + bv.z, acc.w * inv + bv.w};
    float gs[4] = {gv.x, gv.y, gv.z, gv.w};
    float bes[4] = {bev.x, bev.y, bev.z, bev.w};
    float ms[4] = {mv.x, mv.y, mv.z, mv.w};
    float vs[4] = {vv.x, vv.y, vv.z, vv.w};
    float4 rv = {0.f, 0.f, 0.f, 0.f};
    if (resid) rv = *(const float4*)&resid[(size_t)n * HID + c0];
    float rs[4] = {rv.x, rv.y, rv.z, rv.w};
    float out[4];
#pragma unroll
    for (int j = 0; j < 4; j++) {
        float val = vals[j];
        val = (val - ms[j]) * rsqrtf(vs[j] + BN_EPS) * gs[j] + bes[j];
        val += rs[j];
        val = (val > 0.f) ? val : expm1f(val);   // ELU
        out[j] = val;
    }
    float4 ov = {out[0], out[1], out[2], out[3]};
    *(float4*)&outh[(size_t)n * HID + c0] = ov;
}

// ---------------- pooling ----------------
__global__ void pool_kernel(const float* __restrict__ h, const int* __restrict__ gstart,
                            float* __restrict__ pooled) {
    int g = blockIdx.x;
    int c = threadIdx.x;
    int s = gstart[g], e = gstart[g + 1];
    float sum = 0.f, mx = -INFINITY;
    for (int n = s; n < e; n++) {
        float v = h[(size_t)n * HID + c];
        sum += v;
        mx = fmaxf(mx, v);
    }
    int cnt = e - s;
    float mean = sum / fmaxf((float)cnt, 1.f);
    if (cnt == 0) mx = 0.f;
    pooled[(size_t)g * 768 + c] = mean;
    pooled[(size_t)g * 768 + 256 + c] = sum;
    pooled[(size_t)g * 768 + 512 + c] = mx;
}

// ---------------- output heads ----------------
__global__ void head_kernel(const float* __restrict__ pooled,
                            const float* __restrict__ ow0, const float* __restrict__ ob0,
                            const float* __restrict__ ow1, const float* __restrict__ ob1,
                            float* __restrict__ out) {
    int g = blockIdx.x;
    int t = threadIdx.x;
    float a0[3] = {0.f, 0.f, 0.f}, a1[3] = {0.f, 0.f, 0.f};
#pragma unroll
    for (int r = 0; r < 3; r++) {
        int c = r * 256 + t;
        float p = pooled[(size_t)g * 768 + c];
#pragma unroll
        for (int j = 0; j < 3; j++) {
            a0[j] += p * ow0[c * 3 + j];
            a1[j] += p * ow1[c * 3 + j];
        }
    }
    __shared__ float sd[6][256];
#pragma unroll
    for (int j = 0; j < 3; j++) { sd[j][t] = a0[j]; sd[3 + j][t] = a1[j]; }
    __syncthreads();
    for (int off = 128; off; off >>= 1) {
        if (t < off) {
#pragma unroll
            for (int j = 0; j < 6; j++) sd[j][t] += sd[j][t + off];
        }
        __syncthreads();
    }
    if (t < 3) {
        out[g * 3 + t] = sd[t][0] + ob0[t];
        out[1536 + g * 3 + t] = sd[3 + t][0] + ob1[t];
    }
}

// ---------------- launch ----------------
extern "C" void kernel_launch(void* const* d_in, const int* in_sizes, int n_in,
                              void* d_out, int out_size, void* d_ws, size_t ws_size,
                              hipStream_t stream) {
    const float* x     = (const float*)d_in[0];
    const int*   ei    = (const int*)d_in[1];
    const int*   batch = (const int*)d_in[2];
    const float* W[3]  = {(const float*)d_in[3], (const float*)d_in[11], (const float*)d_in[19]};
    const float* AS[3] = {(const float*)d_in[4], (const float*)d_in[12], (const float*)d_in[20]};
    const float* AD[3] = {(const float*)d_in[5], (const float*)d_in[13], (const float*)d_in[21]};
    const float* B[3]  = {(const float*)d_in[6], (const float*)d_in[14], (const float*)d_in[22]};
    const float* GM[3] = {(const float*)d_in[7], (const float*)d_in[15], (const float*)d_in[23]};
    const float* BE[3] = {(const float*)d_in[8], (const float*)d_in[16], (const float*)d_in[24]};
    const float* M[3]  = {(const float*)d_in[9], (const float*)d_in[17], (const float*)d_in[25]};
    const float* V[3]  = {(const float*)d_in[10], (const float*)d_in[18], (const float*)d_in[26]};
    const float* ow0 = (const float*)d_in[27];
    const float* ob0 = (const float*)d_in[28];
    const float* ow1 = (const float*)d_in[29];
    const float* ob1 = (const float*)d_in[30];
    float* out = (float*)d_out;

    // workspace carve
    char* p = (char*)d_ws;
    int* rowptr = (int*)p;  p += (size_t)(N_NODES + 1) * 4;
    int* fill   = (int*)p;  p += (size_t)N_NODES * 4;
    int* esrc   = (int*)p;  p += (size_t)EP * 4;
    int* gstart = (int*)p;  p += (size_t)(G_GRAPHS + 1) * 4;
    p = (char*)(((uintptr_t)p + 255) & ~(uintptr_t)255);
    float* hfeat = (float*)p; p += (size_t)N_NODES * HID * 4;
    float* curh  = (float*)p; p += (size_t)N_NODES * HID * 4;
    float* ssrc  = (float*)p; p += (size_t)N_NODES * HEADS * 4;
    float* sdst  = (float*)p; p += (size_t)N_NODES * HEADS * 4;
    float* pooled = (float*)p; p += (size_t)G_GRAPHS * 768 * 4;

    // CSR build
    hipMemsetAsync(fill, 0, (size_t)N_NODES * 4, stream);
    hist_kernel<<<(EP + 255) / 256, 256, 0, stream>>>(ei, fill);
    scan_kernel<<<1, 1024, 0, stream>>>(fill, rowptr);
    scatter_kernel<<<(EP + 255) / 256, 256, 0, stream>>>(ei, fill, esrc);
    gstart_kernel<<<(G_GRAPHS + 64) / 64, 64, 0, stream>>>(batch, gstart);

    dim3 ggrid((N_NODES + 63) / 64, 4);
    int sgrid = (N_NODES * HEADS + 255) / 256;
    int agrid = (N_NODES + 3) / 4;

    // layer 1 (input x, K=128, no residual)
    gemm_kernel<<<ggrid, 256, 0, stream>>>(x, W[0], hfeat, N_NODES, 128);
    score_kernel<<<sgrid, 256, 0, stream>>>(hfeat, AS[0], AD[0], ssrc, sdst);
    agg_kernel<<<agrid, 256, 0, stream>>>(hfeat, ssrc, sdst, rowptr, esrc,
                                          B[0], GM[0], BE[0], M[0], V[0],
                                          nullptr, curh);
    // layers 2,3 (K=256, residual)
    for (int l = 1; l < 3; l++) {
        gemm_kernel<<<ggrid, 256, 0, stream>>>(curh, W[l], hfeat, N_NODES, 256);
        score_kernel<<<sgrid, 256, 0, stream>>>(hfeat, AS[l], AD[l], ssrc, sdst);
        agg_kernel<<<agrid, 256, 0, stream>>>(hfeat, ssrc, sdst, rowptr, esrc,
                                              B[l], GM[l], BE[l], M[l], V[l],
                                              curh, curh);
    }

    // pooling + heads
    pool_kernel<<<G_GRAPHS, 256, 0, stream>>>(curh, gstart, pooled);
    head_kernel<<<G_GRAPHS, 256, 0, stream>>>(pooled, ow0, ob0, ow1, ob1, out);
}

// Round 2
// 739.775 us; speedup vs baseline: 1.5132x; 1.5132x over previous
//
#include <hip/hip_runtime.h>
#include <hip/hip_bf16.h>
#include <math.h>

#define N_NODES 50000
#define N_EDGES 800000
#define EP (N_EDGES + N_NODES)   // edges + self loops
#define G_GRAPHS 512
#define HID 256
#define HEADS 8
#define NEG_SLOPE 0.2f
#define BN_EPS 1e-5f

typedef __attribute__((ext_vector_type(8))) short short8;
typedef __attribute__((ext_vector_type(4))) float floatx4;

__device__ __forceinline__ float bf2f(ushort u) {
    return __uint_as_float(((unsigned)u) << 16);
}
__device__ __forceinline__ ushort f2bf(float f) {
    unsigned u = __float_as_uint(f);
    u += 0x7fff + ((u >> 16) & 1);   // RNE
    return (ushort)(u >> 16);
}

// ---------------- CSR build ----------------

__global__ void hist_kernel(const int* __restrict__ ei, int* __restrict__ fill) {
    int e = blockIdx.x * 256 + threadIdx.x;
    if (e >= EP) return;
    int d = (e < N_EDGES) ? ei[N_EDGES + e] : (e - N_EDGES);
    atomicAdd(&fill[d], 1);
}

__global__ void scan_kernel(int* __restrict__ fill, int* __restrict__ rowptr) {
    __shared__ int sdata[1024];
    int tid = threadIdx.x;
    int carry = 0;
    const int NCH = (N_NODES + 1023) / 1024;
    for (int ch = 0; ch < NCH; ch++) {
        int idx = ch * 1024 + tid;
        int v = (idx < N_NODES) ? fill[idx] : 0;
        sdata[tid] = v;
        __syncthreads();
        for (int off = 1; off < 1024; off <<= 1) {
            int x = 0;
            if (tid >= off) x = sdata[tid - off];
            __syncthreads();
            sdata[tid] += x;
            __syncthreads();
        }
        int excl = carry + sdata[tid] - v;
        if (idx < N_NODES) { rowptr[idx] = excl; fill[idx] = excl; }
        carry += sdata[1023];
        __syncthreads();
    }
    if (tid == 0) rowptr[N_NODES] = carry;
}

__global__ void scatter_kernel(const int* __restrict__ ei, int* __restrict__ fill,
                               int* __restrict__ esrc) {
    int e = blockIdx.x * 256 + threadIdx.x;
    if (e >= EP) return;
    int s, d;
    if (e < N_EDGES) { s = ei[e]; d = ei[N_EDGES + e]; }
    else             { s = d = e - N_EDGES; }
    int pos = atomicAdd(&fill[d], 1);
    esrc[pos] = s;
}

__global__ void gstart_kernel(const int* __restrict__ batch, int* __restrict__ gstart) {
    int g = blockIdx.x * 64 + threadIdx.x;
    if (g > G_GRAPHS) return;
    int lo = 0, hi = N_NODES;
    while (lo < hi) { int mid = (lo + hi) >> 1; if (batch[mid] < g) lo = mid + 1; else hi = mid; }
    gstart[g] = lo;
}

// ---------------- conversions ----------------

__global__ void cvt_kernel(const float* __restrict__ in, ushort* __restrict__ out, int n4) {
    int i = blockIdx.x * 256 + threadIdx.x;
    if (i >= n4) return;
    float4 v = *(const float4*)&in[(size_t)i * 4];
    ushort4 o = {f2bf(v.x), f2bf(v.y), f2bf(v.z), f2bf(v.w)};
    *(ushort4*)&out[(size_t)i * 4] = o;
}

// Wt[c][k] = bf16(W[k][c]) : K-major weights for MFMA B-operand
__global__ void wt_kernel(const float* __restrict__ W, ushort* __restrict__ Wt, int K) {
    int c = blockIdx.x;
    int k = threadIdx.x;
    if (k < K) Wt[(size_t)c * K + k] = f2bf(W[(size_t)k * HID + c]);
}

// ---------------- MFMA GEMM: C[M,256] = A[M,K] @ Wt[256,K]^T (bf16 in/out) ----------------
// 128x128 tile, BK=64, 4 waves (2x2), each wave 64x64 = 4x4 frags of 16x16x32.
#define BM 128
#define BN 128
#define BK 64

__global__ __launch_bounds__(256) void gemm_kernel(
    const ushort* __restrict__ A, const ushort* __restrict__ Bt,
    ushort* __restrict__ C, int M, int K)
{
    __shared__ __align__(16) char As[BM * BK * 2];   // 16KB, [row][64 bf16], xor-swizzled content
    __shared__ __align__(16) char Bs[BN * BK * 2];   // 16KB

    int t = threadIdx.x;
    int w = t >> 6, lane = t & 63;
    int bm = blockIdx.x * BM, bn = blockIdx.y * BN;
    int wr = (w >> 1) * 64, wc = (w & 1) * 64;

    floatx4 acc[4][4] = {};

    int l8 = lane >> 3;                        // row within 8-row chunk
    int cb = ((lane & 7) << 4) ^ ((l8 & 7) << 4);  // pre-swizzled source byte in 128B row-slice
    int rsw = (lane & 7) << 4;                 // read-side swizzle for frag rows

    for (int k0 = 0; k0 < K; k0 += BK) {
#pragma unroll
        for (int c = 0; c < 4; c++) {
            int q = w * 4 + c;                 // chunk 0..15, rows q*8..q*8+7
            int row = q * 8 + l8;
            int ar = bm + row; if (ar > M - 1) ar = M - 1;
            const char* src = (const char*)A + ((size_t)ar * K + k0) * 2 + cb;
            __builtin_amdgcn_global_load_lds(
                (const __attribute__((address_space(1))) void*)src,
                (__attribute__((address_space(3))) void*)&As[q * 1024], 16, 0, 0);
            int br = bn + row;                 // Bt row (output col) < 256
            const char* srcb = (const char*)Bt + ((size_t)br * K + k0) * 2 + cb;
            __builtin_amdgcn_global_load_lds(
                (const __attribute__((address_space(1))) void*)srcb,
                (__attribute__((address_space(3))) void*)&Bs[q * 1024], 16, 0, 0);
        }
        __syncthreads();

#pragma unroll
        for (int ks = 0; ks < 2; ks++) {
            int kb = ks * 64 + ((lane >> 4) << 4);   // byte offset of this lane's 8 bf16 along k
            short8 a[4], b[4];
#pragma unroll
            for (int m = 0; m < 4; m++) {
                int row = wr + m * 16 + (lane & 15);
                a[m] = *(const short8*)&As[row * 128 + (kb ^ rsw)];
            }
#pragma unroll
            for (int n = 0; n < 4; n++) {
                int row = wc + n * 16 + (lane & 15);
                b[n] = *(const short8*)&Bs[row * 128 + (kb ^ rsw)];
            }
#pragma unroll
            for (int m = 0; m < 4; m++)
#pragma unroll
                for (int n = 0; n < 4; n++)
                    acc[m][n] = __builtin_amdgcn_mfma_f32_16x16x32_bf16(a[m], b[n], acc[m][n], 0, 0, 0);
        }
        __syncthreads();
    }

    int cl = lane & 15, rh = lane >> 4;
#pragma unroll
    for (int m = 0; m < 4; m++) {
#pragma unroll
        for (int r = 0; r < 4; r++) {
            int row = bm + wr + m * 16 + rh * 4 + r;
            if (row < M) {
                size_t base = (size_t)row * HID + bn + wc;
#pragma unroll
                for (int n = 0; n < 4; n++)
                    C[base + n * 16 + cl] = f2bf(acc[m][n][r]);
            }
        }
    }
}

// ---------------- attention scores s_src/s_dst [N,8] ----------------
__global__ void score_kernel(const ushort* __restrict__ hb,
                             const float* __restrict__ asrc,
                             const float* __restrict__ adst,
                             float* __restrict__ ssrc, float* __restrict__ sdst) {
    int idx = blockIdx.x * 256 + threadIdx.x;
    if (idx >= N_NODES * HEADS) return;
    int n = idx >> 3, h = idx & 7;
    const ushort* hp = &hb[(size_t)n * HID + h * 32];
    const float* ap = &asrc[h * 32];
    const float* dp = &adst[h * 32];
    float s1 = 0.f, s2 = 0.f;
#pragma unroll
    for (int j = 0; j < 32; j++) {
        float v = bf2f(hp[j]);
        s1 += v * ap[j];
        s2 += v * dp[j];
    }
    ssrc[idx] = s1;
    sdst[idx] = s2;
}

// ---------------- aggregation: one wave per node ----------------
__global__ __launch_bounds__(256) void agg_kernel(
    const ushort* __restrict__ hb, const float* __restrict__ ssrc,
    const float* __restrict__ sdst, const int* __restrict__ rowptr,
    const int* __restrict__ esrc, const float* __restrict__ bias,
    const float* __restrict__ gam, const float* __restrict__ bet,
    const float* __restrict__ bmean, const float* __restrict__ bvar,
    const float* __restrict__ resid, float* __restrict__ outh,
    ushort* __restrict__ outb) {
    int wid = threadIdx.x >> 6;
    int lane = threadIdx.x & 63;
    int n = blockIdx.x * 4 + wid;
    if (n >= N_NODES) return;
    int start = rowptr[n], end = rowptr[n + 1];
    int head = lane >> 3;

    float sd[8];
    {
        float4 t0 = *(const float4*)&sdst[(size_t)n * 8];
        float4 t1 = *(const float4*)&sdst[(size_t)n * 8 + 4];
        sd[0] = t0.x; sd[1] = t0.y; sd[2] = t0.z; sd[3] = t0.w;
        sd[4] = t1.x; sd[5] = t1.y; sd[6] = t1.z; sd[7] = t1.w;
    }

    // phase 1: per-head max over incoming edges
    float lmax[8];
#pragma unroll
    for (int h = 0; h < 8; h++) lmax[h] = -INFINITY;
    for (int i = start + lane; i < end; i += 64) {
        int s = esrc[i];
        float4 t0 = *(const float4*)&ssrc[(size_t)s * 8];
        float4 t1 = *(const float4*)&ssrc[(size_t)s * 8 + 4];
        float sv[8] = {t0.x, t0.y, t0.z, t0.w, t1.x, t1.y, t1.z, t1.w};
#pragma unroll
        for (int h = 0; h < 8; h++) {
            float a = sv[h] + sd[h];
            a = (a >= 0.f) ? a : NEG_SLOPE * a;
            lmax[h] = fmaxf(lmax[h], a);
        }
    }
#pragma unroll
    for (int off = 32; off; off >>= 1) {
#pragma unroll
        for (int h = 0; h < 8; h++)
            lmax[h] = fmaxf(lmax[h], __shfl_xor(lmax[h], off, 64));
    }
    float mxh = lmax[head];
    float sdh = sd[head];

    // phase 2: exp-weighted message accumulation (bf16 gathers, fp32 accumulate)
    float z = 0.f;
    float4 acc = {0.f, 0.f, 0.f, 0.f};
    int i = start;
    for (; i + 1 < end; i += 2) {
        int s0 = esrc[i], s1 = esrc[i + 1];
        float a0 = ssrc[(size_t)s0 * 8 + head] + sdh;
        float a1 = ssrc[(size_t)s1 * 8 + head] + sdh;
        a0 = (a0 >= 0.f) ? a0 : NEG_SLOPE * a0;
        a1 = (a1 >= 0.f) ? a1 : NEG_SLOPE * a1;
        float e0 = __expf(a0 - mxh);
        float e1 = __expf(a1 - mxh);
        ushort4 h0 = *(const ushort4*)&hb[(size_t)s0 * HID + lane * 4];
        ushort4 h1 = *(const ushort4*)&hb[(size_t)s1 * HID + lane * 4];
        z += e0 + e1;
        acc.x += e0 * bf2f(h0.x) + e1 * bf2f(h1.x);
        acc.y += e0 * bf2f(h0.y) + e1 * bf2f(h1.y);
        acc.z += e0 * bf2f(h0.z) + e1 * bf2f(h1.z);
        acc.w += e0 * bf2f(h0.w) + e1 * bf2f(h1.w);
    }
    if (i < end) {
        int s = esrc[i];
        float a = ssrc[(size_t)s * 8 + head] + sdh;
        a = (a >= 0.f) ? a : NEG_SLOPE * a;
        float e = __expf(a - mxh);
        ushort4 hv = *(const ushort4*)&hb[(size_t)s * HID + lane * 4];
        z += e;
        acc.x += e * bf2f(hv.x); acc.y += e * bf2f(hv.y);
        acc.z += e * bf2f(hv.z); acc.w += e * bf2f(hv.w);
    }

    float inv = 1.f / (z + 1e-16f);
    int c0 = lane * 4;
    float4 bv = *(const float4*)&bias[c0];
    float4 gv = *(const float4*)&gam[c0];
    float4 bev = *(const float4*)&bet[c0];
    float4 mv = *(const float4*)&bmean[c0];
    float4 vv = *(const float4*)&bvar[c0];
    float vals[4] = {acc.x * inv + bv.x, acc.y * inv + bv.y,
                     acc.z * inv + bv.z, acc.w * inv + bv.w};
    float gs[4] = {gv.x, gv.y, gv.z, gv.w};
    float bes[4] = {bev.x, bev.y, bev.z, bev.w};
    float ms[4] = {mv.x, mv.y, mv.z, mv.w};
    float vs[4] = {vv.x, vv.y, vv.z, vv.w};
    float4 rv = {0.f, 0.f, 0.f, 0.f};
    if (resid) rv = *(const float4*)&resid[(size_t)n * HID + c0];
    float rs[4] = {rv.x, rv.y, rv.z, rv.w};
    float out[4];
#pragma unroll
    for (int j = 0; j < 4; j++) {
        float val = vals[j];
        val = (val - ms[j]) * rsqrtf(vs[j] + BN_EPS) * gs[j] + bes[j];
        val += rs[j];
        val = (val > 0.f) ? val : expm1f(val);   // ELU
        out[j] = val;
    }
    float4 ov = {out[0], out[1], out[2], out[3]};
    *(float4*)&outh[(size_t)n * HID + c0] = ov;
    if (outb) {
        ushort4 ob = {f2bf(out[0]), f2bf(out[1]), f2bf(out[2]), f2bf(out[3])};
        *(ushort4*)&outb[(size_t)n * HID + c0] = ob;
    }
}

// ---------------- pooling ----------------
__global__ void pool_kernel(const float* __restrict__ h, const int* __restrict__ gstart,
                            float* __restrict__ pooled) {
    int g = blockIdx.x;
    int c = threadIdx.x;
    int s = gstart[g], e = gstart[g + 1];
    float sum = 0.f, mx = -INFINITY;
    for (int n = s; n < e; n++) {
        float v = h[(size_t)n * HID + c];
        sum += v;
        mx = fmaxf(mx, v);
    }
    int cnt = e - s;
    float mean = sum / fmaxf((float)cnt, 1.f);
    if (cnt == 0) mx = 0.f;
    pooled[(size_t)g * 768 + c] = mean;
    pooled[(size_t)g * 768 + 256 + c] = sum;
    pooled[(size_t)g * 768 + 512 + c] = mx;
}

// ---------------- output heads ----------------
__global__ void head_kernel(const float* __restrict__ pooled,
                            const float* __restrict__ ow0, const float* __restrict__ ob0,
                            const float* __restrict__ ow1, const float* __restrict__ ob1,
                            float* __restrict__ out) {
    int g = blockIdx.x;
    int t = threadIdx.x;
    float a0[3] = {0.f, 0.f, 0.f}, a1[3] = {0.f, 0.f, 0.f};
#pragma unroll
    for (int r = 0; r < 3; r++) {
        int c = r * 256 + t;
        float p = pooled[(size_t)g * 768 + c];
#pragma unroll
        for (int j = 0; j < 3; j++) {
            a0[j] += p * ow0[c * 3 + j];
            a1[j] += p * ow1[c * 3 + j];
        }
    }
    __shared__ float sd[6][256];
#pragma unroll
    for (int j = 0; j < 3; j++) { sd[j][t] = a0[j]; sd[3 + j][t] = a1[j]; }
    __syncthreads();
    for (int off = 128; off; off >>= 1) {
        if (t < off) {
#pragma unroll
            for (int j = 0; j < 6; j++) sd[j][t] += sd[j][t + off];
        }
        __syncthreads();
    }
    if (t < 3) {
        out[g * 3 + t] = sd[t][0] + ob0[t];
        out[1536 + g * 3 + t] = sd[3 + t][0] + ob1[t];
    }
}

// ---------------- launch ----------------
extern "C" void kernel_launch(void* const* d_in, const int* in_sizes, int n_in,
                              void* d_out, int out_size, void* d_ws, size_t ws_size,
                              hipStream_t stream) {
    const float* x     = (const float*)d_in[0];
    const int*   ei    = (const int*)d_in[1];
    const int*   batch = (const int*)d_in[2];
    const float* W[3]  = {(const float*)d_in[3], (const float*)d_in[11], (const float*)d_in[19]};
    const float* AS[3] = {(const float*)d_in[4], (const float*)d_in[12], (const float*)d_in[20]};
    const float* AD[3] = {(const float*)d_in[5], (const float*)d_in[13], (const float*)d_in[21]};
    const float* B[3]  = {(const float*)d_in[6], (const float*)d_in[14], (const float*)d_in[22]};
    const float* GM[3] = {(const float*)d_in[7], (const float*)d_in[15], (const float*)d_in[23]};
    const float* BE[3] = {(const float*)d_in[8], (const float*)d_in[16], (const float*)d_in[24]};
    const float* M[3]  = {(const float*)d_in[9], (const float*)d_in[17], (const float*)d_in[25]};
    const float* V[3]  = {(const float*)d_in[10], (const float*)d_in[18], (const float*)d_in[26]};
    const float* ow0 = (const float*)d_in[27];
    const float* ob0 = (const float*)d_in[28];
    const float* ow1 = (const float*)d_in[29];
    const float* ob1 = (const float*)d_in[30];
    float* out = (float*)d_out;

    // workspace carve
    char* p = (char*)d_ws;
    int* rowptr = (int*)p;  p += (size_t)(N_NODES + 1) * 4;
    int* fill   = (int*)p;  p += (size_t)N_NODES * 4;
    int* esrc   = (int*)p;  p += (size_t)EP * 4;
    int* gstart = (int*)p;  p += (size_t)(G_GRAPHS + 1) * 4;
    p = (char*)(((uintptr_t)p + 255) & ~(uintptr_t)255);
    ushort* hb    = (ushort*)p; p += (size_t)N_NODES * HID * 2;      // GEMM out (bf16)
    float*  curh  = (float*)p;  p += (size_t)N_NODES * HID * 4;      // layer out (fp32)
    ushort* curhb = (ushort*)p; p += (size_t)N_NODES * HID * 2;      // layer out (bf16)
    ushort* xb    = (ushort*)p; p += (size_t)N_NODES * 128 * 2;      // x bf16
    ushort* Wt0   = (ushort*)p; p += (size_t)256 * 128 * 2;
    ushort* Wt1   = (ushort*)p; p += (size_t)256 * 256 * 2;
    ushort* Wt2   = (ushort*)p; p += (size_t)256 * 256 * 2;
    float* ssrc   = (float*)p;  p += (size_t)N_NODES * HEADS * 4;
    float* sdst   = (float*)p;  p += (size_t)N_NODES * HEADS * 4;
    float* pooled = (float*)p;  p += (size_t)G_GRAPHS * 768 * 4;

    // CSR build
    hipMemsetAsync(fill, 0, (size_t)N_NODES * 4, stream);
    hist_kernel<<<(EP + 255) / 256, 256, 0, stream>>>(ei, fill);
    scan_kernel<<<1, 1024, 0, stream>>>(fill, rowptr);
    scatter_kernel<<<(EP + 255) / 256, 256, 0, stream>>>(ei, fill, esrc);
    gstart_kernel<<<(G_GRAPHS + 64) / 64, 64, 0, stream>>>(batch, gstart);

    // bf16 conversions
    cvt_kernel<<<(N_NODES * 128 / 4 + 255) / 256, 256, 0, stream>>>(x, xb, N_NODES * 128 / 4);
    wt_kernel<<<256, 256, 0, stream>>>(W[0], Wt0, 128);
    wt_kernel<<<256, 256, 0, stream>>>(W[1], Wt1, 256);
    wt_kernel<<<256, 256, 0, stream>>>(W[2], Wt2, 256);
    const ushort* Wt[3] = {Wt0, Wt1, Wt2};

    dim3 ggrid((N_NODES + BM - 1) / BM, HID / BN);
    int sgrid = (N_NODES * HEADS + 255) / 256;
    int agrid = (N_NODES + 3) / 4;

    // layer 1 (input xb, K=128, no residual)
    gemm_kernel<<<ggrid, 256, 0, stream>>>(xb, Wt[0], hb, N_NODES, 128);
    score_kernel<<<sgrid, 256, 0, stream>>>(hb, AS[0], AD[0], ssrc, sdst);
    agg_kernel<<<agrid, 256, 0, stream>>>(hb, ssrc, sdst, rowptr, esrc,
                                          B[0], GM[0], BE[0], M[0], V[0],
                                          nullptr, curh, curhb);
    // layers 2,3 (K=256, residual)
    for (int l = 1; l < 3; l++) {
        gemm_kernel<<<ggrid, 256, 0, stream>>>(curhb, Wt[l], hb, N_NODES, 256);
        score_kernel<<<sgrid, 256, 0, stream>>>(hb, AS[l], AD[l], ssrc, sdst);
        agg_kernel<<<agrid, 256, 0, stream>>>(hb, ssrc, sdst, rowptr, esrc,
                                              B[l], GM[l], BE[l], M[l], V[l],
                                              curh, curh, (l == 1) ? curhb : nullptr);
    }

    // pooling + heads
    pool_kernel<<<G_GRAPHS, 256, 0, stream>>>(curh, gstart, pooled);
    head_kernel<<<G_GRAPHS, 256, 0, stream>>>(pooled, ow0, ob0, ow1, ob1, out);
}

// Round 4
// 622.247 us; speedup vs baseline: 1.7990x; 1.1889x over previous
//
#include <hip/hip_runtime.h>
#include <hip/hip_bf16.h>
#include <math.h>

#define N_NODES 50000
#define N_EDGES 800000
#define EP (N_EDGES + N_NODES)   // edges + self loops
#define G_GRAPHS 512
#define HID 256
#define HEADS 8
#define NEG_SLOPE 0.2f
#define BN_EPS 1e-5f
#define NB_SCAN ((N_NODES + 1023) / 1024)   // 49

typedef __attribute__((ext_vector_type(8))) short short8;
typedef __attribute__((ext_vector_type(8))) unsigned short ushort8v;
typedef __attribute__((ext_vector_type(4))) float floatx4;

__device__ __forceinline__ float bf2f(ushort u) {
    return __uint_as_float(((unsigned)u) << 16);
}
__device__ __forceinline__ ushort f2bf(float f) {
    unsigned u = __float_as_uint(f);
    u += 0x7fff + ((u >> 16) & 1);   // RNE
    return (ushort)(u >> 16);
}

// ---------------- CSR build ----------------

__global__ void hist_kernel(const int* __restrict__ ei, int* __restrict__ fill) {
    int e = blockIdx.x * 256 + threadIdx.x;
    if (e >= EP) return;
    int d = (e < N_EDGES) ? ei[N_EDGES + e] : (e - N_EDGES);
    atomicAdd(&fill[d], 1);
}

// block-level scan: rowptr[idx] = exclusive-within-block, bsum[b] = block total
__global__ void scan1_kernel(const int* __restrict__ fill, int* __restrict__ rowptr,
                             int* __restrict__ bsum) {
    __shared__ int sdata[1024];
    int tid = threadIdx.x;
    int idx = blockIdx.x * 1024 + tid;
    int v = (idx < N_NODES) ? fill[idx] : 0;
    sdata[tid] = v;
    __syncthreads();
    for (int off = 1; off < 1024; off <<= 1) {
        int x = (tid >= off) ? sdata[tid - off] : 0;
        __syncthreads();
        sdata[tid] += x;
        __syncthreads();
    }
    if (idx < N_NODES) rowptr[idx] = sdata[tid] - v;
    if (tid == 1023) bsum[blockIdx.x] = sdata[1023];
}

// wave scan of NB_SCAN block sums (in place -> exclusive), bsum[NB_SCAN] = total
__global__ void scan2_kernel(int* __restrict__ bsum) {
    int lane = threadIdx.x;
    int v = (lane < NB_SCAN) ? bsum[lane] : 0;
    int incl = v;
#pragma unroll
    for (int off = 1; off < 64; off <<= 1) {
        int x = __shfl_up(incl, off, 64);
        if (lane >= off) incl += x;
    }
    if (lane < NB_SCAN) bsum[lane] = incl - v;
    if (lane == NB_SCAN - 1) bsum[NB_SCAN] = incl;
}

__global__ void scan3_kernel(int* __restrict__ rowptr, int* __restrict__ fill,
                             const int* __restrict__ bsum) {
    int idx = blockIdx.x * 1024 + threadIdx.x;
    if (idx < N_NODES) {
        int e = rowptr[idx] + bsum[blockIdx.x];
        rowptr[idx] = e;
        fill[idx] = e;
    }
    if (idx == N_NODES) rowptr[N_NODES] = bsum[NB_SCAN];
}

__global__ void scatter_kernel(const int* __restrict__ ei, int* __restrict__ fill,
                               int* __restrict__ esrc) {
    int e = blockIdx.x * 256 + threadIdx.x;
    if (e >= EP) return;
    int s, d;
    if (e < N_EDGES) { s = ei[e]; d = ei[N_EDGES + e]; }
    else             { s = d = e - N_EDGES; }
    int pos = atomicAdd(&fill[d], 1);
    esrc[pos] = s;
}

__global__ void gstart_kernel(const int* __restrict__ batch, int* __restrict__ gstart) {
    int g = blockIdx.x * 64 + threadIdx.x;
    if (g > G_GRAPHS) return;
    int lo = 0, hi = N_NODES;
    while (lo < hi) { int mid = (lo + hi) >> 1; if (batch[mid] < g) lo = mid + 1; else hi = mid; }
    gstart[g] = lo;
}

// ---------------- conversions ----------------

__global__ void cvt_kernel(const float* __restrict__ in, ushort* __restrict__ out, int n4) {
    int i = blockIdx.x * 256 + threadIdx.x;
    if (i >= n4) return;
    float4 v = *(const float4*)&in[(size_t)i * 4];
    ushort4 o = {f2bf(v.x), f2bf(v.y), f2bf(v.z), f2bf(v.w)};
    *(ushort4*)&out[(size_t)i * 4] = o;
}

// Wt[c][k] = bf16(W[k][c]) for all three layers; gridDim=(256,3)
__global__ void wt_all_kernel(const float* __restrict__ W0, const float* __restrict__ W1,
                              const float* __restrict__ W2, ushort* __restrict__ Wt0,
                              ushort* __restrict__ Wt1, ushort* __restrict__ Wt2) {
    int m = blockIdx.y;
    const float* W = (m == 0) ? W0 : (m == 1) ? W1 : W2;
    ushort* Wt = (m == 0) ? Wt0 : (m == 1) ? Wt1 : Wt2;
    int K = (m == 0) ? 128 : 256;
    int c = blockIdx.x, k = threadIdx.x;
    if (k < K) Wt[(size_t)c * K + k] = f2bf(W[(size_t)k * HID + c]);
}

// ---------------- MFMA GEMM: C[M,256] = A[M,K] @ Wt[256,K]^T (bf16 in/out) ----------------
#define BM 128
#define BN 128
#define BK 64

__global__ __launch_bounds__(256) void gemm_kernel(
    const ushort* __restrict__ A, const ushort* __restrict__ Bt,
    ushort* __restrict__ C, int M, int K)
{
    __shared__ __align__(16) char As[BM * BK * 2];
    __shared__ __align__(16) char Bs[BN * BK * 2];

    int t = threadIdx.x;
    int w = t >> 6, lane = t & 63;
    int bm = blockIdx.x * BM, bn = blockIdx.y * BN;
    int wr = (w >> 1) * 64, wc = (w & 1) * 64;

    floatx4 acc[4][4] = {};

    int l8 = lane >> 3;
    int cb = ((lane & 7) << 4) ^ ((l8 & 7) << 4);  // pre-swizzled source byte
    int rsw = (lane & 7) << 4;                     // read-side swizzle

    for (int k0 = 0; k0 < K; k0 += BK) {
#pragma unroll
        for (int c = 0; c < 4; c++) {
            int q = w * 4 + c;
            int row = q * 8 + l8;
            int ar = bm + row; if (ar > M - 1) ar = M - 1;
            const char* src = (const char*)A + ((size_t)ar * K + k0) * 2 + cb;
            __builtin_amdgcn_global_load_lds(
                (const __attribute__((address_space(1))) void*)src,
                (__attribute__((address_space(3))) void*)&As[q * 1024], 16, 0, 0);
            int br = bn + row;
            const char* srcb = (const char*)Bt + ((size_t)br * K + k0) * 2 + cb;
            __builtin_amdgcn_global_load_lds(
                (const __attribute__((address_space(1))) void*)srcb,
                (__attribute__((address_space(3))) void*)&Bs[q * 1024], 16, 0, 0);
        }
        __syncthreads();

#pragma unroll
        for (int ks = 0; ks < 2; ks++) {
            int kb = ks * 64 + ((lane >> 4) << 4);
            short8 a[4], b[4];
#pragma unroll
            for (int m = 0; m < 4; m++) {
                int row = wr + m * 16 + (lane & 15);
                a[m] = *(const short8*)&As[row * 128 + (kb ^ rsw)];
            }
#pragma unroll
            for (int n = 0; n < 4; n++) {
                int row = wc + n * 16 + (lane & 15);
                b[n] = *(const short8*)&Bs[row * 128 + (kb ^ rsw)];
            }
#pragma unroll
            for (int m = 0; m < 4; m++)
#pragma unroll
                for (int n = 0; n < 4; n++)
                    acc[m][n] = __builtin_amdgcn_mfma_f32_16x16x32_bf16(a[m], b[n], acc[m][n], 0, 0, 0);
        }
        __syncthreads();
    }

    int cl = lane & 15, rh = lane >> 4;
#pragma unroll
    for (int m = 0; m < 4; m++) {
#pragma unroll
        for (int r = 0; r < 4; r++) {
            int row = bm + wr + m * 16 + rh * 4 + r;
            if (row < M) {
                size_t base = (size_t)row * HID + bn + wc;
#pragma unroll
                for (int n = 0; n < 4; n++)
                    C[base + n * 16 + cl] = f2bf(acc[m][n][r]);
            }
        }
    }
}

// ---------------- attention scores s_src/s_dst [N,8] ----------------
__global__ void score_kernel(const ushort* __restrict__ hb,
                             const float* __restrict__ asrc,
                             const float* __restrict__ adst,
                             float* __restrict__ ssrc, float* __restrict__ sdst) {
    int idx = blockIdx.x * 256 + threadIdx.x;
    if (idx >= N_NODES * HEADS) return;
    int n = idx >> 3, h = idx & 7;
    const ushort* hp = &hb[(size_t)n * HID + h * 32];
    const float* ap = &asrc[h * 32];
    const float* dp = &adst[h * 32];
    float s1 = 0.f, s2 = 0.f;
#pragma unroll
    for (int j = 0; j < 32; j++) {
        float v = bf2f(hp[j]);
        s1 += v * ap[j];
        s2 += v * dp[j];
    }
    ssrc[idx] = s1;
    sdst[idx] = s2;
}

// ---------------- aggregation: one wave per node, 2 edge slots x 32 channel-lanes ----------
// no max-subtraction: |alpha| <~ 10 here, exp(alpha) safe in fp32 and e/sum(e) is identical
__global__ __launch_bounds__(256) void agg_kernel(
    const ushort* __restrict__ hb, const float* __restrict__ ssrc,
    const float* __restrict__ sdst, const int* __restrict__ rowptr,
    const int* __restrict__ esrc, const float* __restrict__ bias,
    const float* __restrict__ gam, const float* __restrict__ bet,
    const float* __restrict__ bmean, const float* __restrict__ bvar,
    const float* __restrict__ resid, float* __restrict__ outh,
    ushort* __restrict__ outb) {
    int wid = threadIdx.x >> 6;
    int lane = threadIdx.x & 63;
    int n = blockIdx.x * 4 + wid;
    if (n >= N_NODES) return;
    int start = rowptr[n], end = rowptr[n + 1];
    int slot = lane >> 5;        // which edge of a pair
    int cl = lane & 31;          // channel-lane: 8 channels each
    int c0 = cl * 8;
    int head = cl >> 2;          // c0/32
    float sdh = ssrc ? sdst[(size_t)n * 8 + head] : 0.f;

    float z = 0.f;
    float acc[8] = {};
    int i = start + slot;
    for (; i + 2 < end; i += 4) {
        int s0 = esrc[i], s1 = esrc[i + 2];
        float a0 = ssrc[(size_t)s0 * 8 + head] + sdh;
        float a1 = ssrc[(size_t)s1 * 8 + head] + sdh;
        a0 = (a0 >= 0.f) ? a0 : NEG_SLOPE * a0;
        a1 = (a1 >= 0.f) ? a1 : NEG_SLOPE * a1;
        float e0 = __expf(a0);
        float e1 = __expf(a1);
        ushort8v h0 = *(const ushort8v*)&hb[(size_t)s0 * HID + c0];
        ushort8v h1 = *(const ushort8v*)&hb[(size_t)s1 * HID + c0];
        z += e0 + e1;
#pragma unroll
        for (int j = 0; j < 8; j++)
            acc[j] += e0 * bf2f(h0[j]) + e1 * bf2f(h1[j]);
    }
    if (i < end) {
        int s = esrc[i];
        float a = ssrc[(size_t)s * 8 + head] + sdh;
        a = (a >= 0.f) ? a : NEG_SLOPE * a;
        float e = __expf(a);
        ushort8v hv = *(const ushort8v*)&hb[(size_t)s * HID + c0];
        z += e;
#pragma unroll
        for (int j = 0; j < 8; j++)
            acc[j] += e * bf2f(hv[j]);
    }
    // combine the two edge slots
    z += __shfl_xor(z, 32, 64);
#pragma unroll
    for (int j = 0; j < 8; j++)
        acc[j] += __shfl_xor(acc[j], 32, 64);

    if (lane < 32) {
        float inv = 1.f / (z + 1e-16f);
        float4 bv0 = *(const float4*)&bias[c0],   bv1 = *(const float4*)&bias[c0 + 4];
        float4 gv0 = *(const float4*)&gam[c0],    gv1 = *(const float4*)&gam[c0 + 4];
        float4 be0 = *(const float4*)&bet[c0],    be1 = *(const float4*)&bet[c0 + 4];
        float4 mv0 = *(const float4*)&bmean[c0],  mv1 = *(const float4*)&bmean[c0 + 4];
        float4 vv0 = *(const float4*)&bvar[c0],   vv1 = *(const float4*)&bvar[c0 + 4];
        float bs[8] = {bv0.x, bv0.y, bv0.z, bv0.w, bv1.x, bv1.y, bv1.z, bv1.w};
        float gs[8] = {gv0.x, gv0.y, gv0.z, gv0.w, gv1.x, gv1.y, gv1.z, gv1.w};
        float bes[8] = {be0.x, be0.y, be0.z, be0.w, be1.x, be1.y, be1.z, be1.w};
        float ms[8] = {mv0.x, mv0.y, mv0.z, mv0.w, mv1.x, mv1.y, mv1.z, mv1.w};
        float vs[8] = {vv0.x, vv0.y, vv0.z, vv0.w, vv1.x, vv1.y, vv1.z, vv1.w};
        float rs[8] = {};
        if (resid) {
            float4 r0 = *(const float4*)&resid[(size_t)n * HID + c0];
            float4 r1 = *(const float4*)&resid[(size_t)n * HID + c0 + 4];
            rs[0] = r0.x; rs[1] = r0.y; rs[2] = r0.z; rs[3] = r0.w;
            rs[4] = r1.x; rs[5] = r1.y; rs[6] = r1.z; rs[7] = r1.w;
        }
        float out[8];
#pragma unroll
        for (int j = 0; j < 8; j++) {
            float val = acc[j] * inv + bs[j];
            val = (val - ms[j]) * rsqrtf(vs[j] + BN_EPS) * gs[j] + bes[j];
            val += rs[j];
            val = (val > 0.f) ? val : expm1f(val);   // ELU
            out[j] = val;
        }
        if (outh) {
            float4 o0 = {out[0], out[1], out[2], out[3]};
            float4 o1 = {out[4], out[5], out[6], out[7]};
            *(float4*)&outh[(size_t)n * HID + c0] = o0;
            *(float4*)&outh[(size_t)n * HID + c0 + 4] = o1;
        }
        if (outb) {
            ushort8v ob;
#pragma unroll
            for (int j = 0; j < 8; j++) ob[j] = f2bf(out[j]);
            *(ushort8v*)&outb[(size_t)n * HID + c0] = ob;
        }
    }
}

// ---------------- fused pooling + output heads ----------------
__global__ void poolhead_kernel(const ushort* __restrict__ hbf, const int* __restrict__ gstart,
                                const float* __restrict__ ow0, const float* __restrict__ ob0,
                                const float* __restrict__ ow1, const float* __restrict__ ob1,
                                float* __restrict__ out) {
    int g = blockIdx.x;
    int t = threadIdx.x;          // channel
    int s = gstart[g], e = gstart[g + 1];
    float sum = 0.f, mx = -INFINITY;
    for (int n = s; n < e; n++) {
        float v = bf2f(hbf[(size_t)n * HID + t]);
        sum += v;
        mx = fmaxf(mx, v);
    }
    int cnt = e - s;
    float mean = sum / fmaxf((float)cnt, 1.f);
    if (cnt == 0) mx = 0.f;

    float a0[3], a1[3];
#pragma unroll
    for (int j = 0; j < 3; j++) {
        a0[j] = mean * ow0[t * 3 + j] + sum * ow0[(256 + t) * 3 + j] + mx * ow0[(512 + t) * 3 + j];
        a1[j] = mean * ow1[t * 3 + j] + sum * ow1[(256 + t) * 3 + j] + mx * ow1[(512 + t) * 3 + j];
    }
    __shared__ float sd[6][256];
#pragma unroll
    for (int j = 0; j < 3; j++) { sd[j][t] = a0[j]; sd[3 + j][t] = a1[j]; }
    __syncthreads();
    for (int off = 128; off; off >>= 1) {
        if (t < off) {
#pragma unroll
            for (int j = 0; j < 6; j++) sd[j][t] += sd[j][t + off];
        }
        __syncthreads();
    }
    if (t < 3) {
        out[g * 3 + t] = sd[t][0] + ob0[t];
        out[1536 + g * 3 + t] = sd[3 + t][0] + ob1[t];
    }
}

// ---------------- launch ----------------
extern "C" void kernel_launch(void* const* d_in, const int* in_sizes, int n_in,
                              void* d_out, int out_size, void* d_ws, size_t ws_size,
                              hipStream_t stream) {
    const float* x     = (const float*)d_in[0];
    const int*   ei    = (const int*)d_in[1];
    const int*   batch = (const int*)d_in[2];
    const float* W[3]  = {(const float*)d_in[3], (const float*)d_in[11], (const float*)d_in[19]};
    const float* AS[3] = {(const float*)d_in[4], (const float*)d_in[12], (const float*)d_in[20]};
    const float* AD[3] = {(const float*)d_in[5], (const float*)d_in[13], (const float*)d_in[21]};
    const float* B[3]  = {(const float*)d_in[6], (const float*)d_in[14], (const float*)d_in[22]};
    const float* GM[3] = {(const float*)d_in[7], (const float*)d_in[15], (const float*)d_in[23]};
    const float* BE[3] = {(const float*)d_in[8], (const float*)d_in[16], (const float*)d_in[24]};
    const float* M[3]  = {(const float*)d_in[9], (const float*)d_in[17], (const float*)d_in[25]};
    const float* V[3]  = {(const float*)d_in[10], (const float*)d_in[18], (const float*)d_in[26]};
    const float* ow0 = (const float*)d_in[27];
    const float* ob0 = (const float*)d_in[28];
    const float* ow1 = (const float*)d_in[29];
    const float* ob1 = (const float*)d_in[30];
    float* out = (float*)d_out;

    // workspace carve
    char* p = (char*)d_ws;
    int* rowptr = (int*)p;  p += (size_t)(N_NODES + 1) * 4;
    int* fill   = (int*)p;  p += (size_t)N_NODES * 4;
    int* esrc   = (int*)p;  p += (size_t)EP * 4;
    int* gstart = (int*)p;  p += (size_t)(G_GRAPHS + 1) * 4;
    int* bsum   = (int*)p;  p += (size_t)(NB_SCAN + 1) * 4;
    p = (char*)(((uintptr_t)p + 255) & ~(uintptr_t)255);
    ushort* hb    = (ushort*)p; p += (size_t)N_NODES * HID * 2;      // GEMM out (bf16)
    float*  curh  = (float*)p;  p += (size_t)N_NODES * HID * 4;      // layer out (fp32)
    ushort* curhb = (ushort*)p; p += (size_t)N_NODES * HID * 2;      // layer out (bf16)
    ushort* xb    = (ushort*)p; p += (size_t)N_NODES * 128 * 2;      // x bf16
    ushort* Wt0   = (ushort*)p; p += (size_t)256 * 128 * 2;
    ushort* Wt1   = (ushort*)p; p += (size_t)256 * 256 * 2;
    ushort* Wt2   = (ushort*)p; p += (size_t)256 * 256 * 2;
    float* ssrc   = (float*)p;  p += (size_t)N_NODES * HEADS * 4;
    float* sdst   = (float*)p;  p += (size_t)N_NODES * HEADS * 4;

    // CSR build
    hipMemsetAsync(fill, 0, (size_t)N_NODES * 4, stream);
    hist_kernel<<<(EP + 255) / 256, 256, 0, stream>>>(ei, fill);
    scan1_kernel<<<NB_SCAN, 1024, 0, stream>>>(fill, rowptr, bsum);
    scan2_kernel<<<1, 64, 0, stream>>>(bsum);
    scan3_kernel<<<NB_SCAN, 1024, 0, stream>>>(rowptr, fill, bsum);
    scatter_kernel<<<(EP + 255) / 256, 256, 0, stream>>>(ei, fill, esrc);
    gstart_kernel<<<(G_GRAPHS + 64) / 64, 64, 0, stream>>>(batch, gstart);

    // bf16 conversions
    cvt_kernel<<<(N_NODES * 128 / 4 + 255) / 256, 256, 0, stream>>>(x, xb, N_NODES * 128 / 4);
    {
        dim3 wgrid(256, 3);
        wt_all_kernel<<<wgrid, 256, 0, stream>>>(W[0], W[1], W[2], Wt0, Wt1, Wt2);
    }
    const ushort* Wt[3] = {Wt0, Wt1, Wt2};

    dim3 ggrid((N_NODES + BM - 1) / BM, HID / BN);
    int sgrid = (N_NODES * HEADS + 255) / 256;
    int agrid = (N_NODES + 3) / 4;

    // layer 1 (input xb, K=128, no residual)
    gemm_kernel<<<ggrid, 256, 0, stream>>>(xb, Wt[0], hb, N_NODES, 128);
    score_kernel<<<sgrid, 256, 0, stream>>>(hb, AS[0], AD[0], ssrc, sdst);
    agg_kernel<<<agrid, 256, 0, stream>>>(hb, ssrc, sdst, rowptr, esrc,
                                          B[0], GM[0], BE[0], M[0], V[0],
                                          nullptr, curh, curhb);
    // layer 2 (residual, fp32+bf16 out)
    gemm_kernel<<<ggrid, 256, 0, stream>>>(curhb, Wt[1], hb, N_NODES, 256);
    score_kernel<<<sgrid, 256, 0, stream>>>(hb, AS[1], AD[1], ssrc, sdst);
    agg_kernel<<<agrid, 256, 0, stream>>>(hb, ssrc, sdst, rowptr, esrc,
                                          B[1], GM[1], BE[1], M[1], V[1],
                                          curh, curh, curhb);
    // layer 3 (residual, bf16 out only — feeds pooling)
    gemm_kernel<<<ggrid, 256, 0, stream>>>(curhb, Wt[2], hb, N_NODES, 256);
    score_kernel<<<sgrid, 256, 0, stream>>>(hb, AS[2], AD[2], ssrc, sdst);
    agg_kernel<<<agrid, 256, 0, stream>>>(hb, ssrc, sdst, rowptr, esrc,
                                          B[2], GM[2], BE[2], M[2], V[2],
                                          curh, nullptr, curhb);

    // fused pooling + heads
    poolhead_kernel<<<G_GRAPHS, 256, 0, stream>>>(curhb, gstart, ow0, ob0, ow1, ob1, out);
}

// Round 5
// 599.663 us; speedup vs baseline: 1.8668x; 1.0377x over previous
//
#include <hip/hip_runtime.h>
#include <hip/hip_bf16.h>
#include <math.h>

#define N_NODES 50000
#define N_EDGES 800000
#define EP (N_EDGES + N_NODES)   // edges + self loops
#define G_GRAPHS 512
#define HID 256
#define HEADS 8
#define NEG_SLOPE 0.2f
#define BN_EPS 1e-5f
#define NB_SCAN ((N_NODES + 1023) / 1024)   // 49

typedef __attribute__((ext_vector_type(8))) short short8;
typedef __attribute__((ext_vector_type(8))) unsigned short ushort8v;
typedef __attribute__((ext_vector_type(4))) float floatx4;

__device__ __forceinline__ float bf2f(ushort u) {
    return __uint_as_float(((unsigned)u) << 16);
}
__device__ __forceinline__ ushort f2bf(float f) {
    unsigned u = __float_as_uint(f);
    u += 0x7fff + ((u >> 16) & 1);   // RNE
    return (ushort)(u >> 16);
}

// ---------------- CSR build ----------------

__global__ void hist_kernel(const int* __restrict__ ei, int* __restrict__ fill) {
    int e = blockIdx.x * 256 + threadIdx.x;
    if (e >= EP) return;
    int d = (e < N_EDGES) ? ei[N_EDGES + e] : (e - N_EDGES);
    atomicAdd(&fill[d], 1);
}

// block-level scan: rowptr[idx] = exclusive-within-block, bsum[b] = block total
__global__ void scan1_kernel(const int* __restrict__ fill, int* __restrict__ rowptr,
                             int* __restrict__ bsum) {
    __shared__ int sdata[1024];
    int tid = threadIdx.x;
    int idx = blockIdx.x * 1024 + tid;
    int v = (idx < N_NODES) ? fill[idx] : 0;
    sdata[tid] = v;
    __syncthreads();
    for (int off = 1; off < 1024; off <<= 1) {
        int x = (tid >= off) ? sdata[tid - off] : 0;
        __syncthreads();
        sdata[tid] += x;
        __syncthreads();
    }
    if (idx < N_NODES) rowptr[idx] = sdata[tid] - v;
    if (tid == 1023) bsum[blockIdx.x] = sdata[1023];
}

// adds block-prefix (computed locally by wave-scanning bsum) -> rowptr/fill global
__global__ void scan3_kernel(int* __restrict__ rowptr, int* __restrict__ fill,
                             const int* __restrict__ bsum) {
    __shared__ int soff[2];
    int tid = threadIdx.x;
    if (tid < 64) {
        int v = (tid < NB_SCAN) ? bsum[tid] : 0;
        int incl = v;
#pragma unroll
        for (int off = 1; off < 64; off <<= 1) {
            int x = __shfl_up(incl, off, 64);
            if (tid >= off) incl += x;
        }
        if (tid == blockIdx.x) soff[0] = incl - v;
        if (tid == NB_SCAN - 1) soff[1] = incl;
    }
    __syncthreads();
    int idx = blockIdx.x * 1024 + tid;
    if (idx < N_NODES) {
        int e = rowptr[idx] + soff[0];
        rowptr[idx] = e;
        fill[idx] = e;
    }
    if (idx == N_NODES) rowptr[N_NODES] = soff[1];
}

__global__ void scatter_kernel(const int* __restrict__ ei, int* __restrict__ fill,
                               int* __restrict__ esrc) {
    int e = blockIdx.x * 256 + threadIdx.x;
    if (e >= EP) return;
    int s, d;
    if (e < N_EDGES) { s = ei[e]; d = ei[N_EDGES + e]; }
    else             { s = d = e - N_EDGES; }
    int pos = atomicAdd(&fill[d], 1);
    esrc[pos] = s;
}

__global__ void gstart_kernel(const int* __restrict__ batch, int* __restrict__ gstart) {
    int g = blockIdx.x * 64 + threadIdx.x;
    if (g > G_GRAPHS) return;
    int lo = 0, hi = N_NODES;
    while (lo < hi) { int mid = (lo + hi) >> 1; if (batch[mid] < g) lo = mid + 1; else hi = mid; }
    gstart[g] = lo;
}

// ---------------- conversions ----------------

__global__ void cvt_kernel(const float* __restrict__ in, ushort* __restrict__ out, int n4) {
    int i = blockIdx.x * 256 + threadIdx.x;
    if (i >= n4) return;
    float4 v = *(const float4*)&in[(size_t)i * 4];
    ushort4 o = {f2bf(v.x), f2bf(v.y), f2bf(v.z), f2bf(v.w)};
    *(ushort4*)&out[(size_t)i * 4] = o;
}

// Wt[c][k] = bf16(W[k][c]) for all three layers; gridDim=(256,3)
__global__ void wt_all_kernel(const float* __restrict__ W0, const float* __restrict__ W1,
                              const float* __restrict__ W2, ushort* __restrict__ Wt0,
                              ushort* __restrict__ Wt1, ushort* __restrict__ Wt2) {
    int m = blockIdx.y;
    const float* W = (m == 0) ? W0 : (m == 1) ? W1 : W2;
    ushort* Wt = (m == 0) ? Wt0 : (m == 1) ? Wt1 : Wt2;
    int K = (m == 0) ? 128 : 256;
    int c = blockIdx.x, k = threadIdx.x;
    if (k < K) Wt[(size_t)c * K + k] = f2bf(W[(size_t)k * HID + c]);
}

// ---------------- MFMA GEMM: C[M,256] = A[M,K] @ Wt[256,K]^T (bf16 in/out) ----------------
// 128x128 tile, BK=64, double-buffered LDS, counted vmcnt (loads fly across barriers)
#define BM 128
#define BN 128
#define BK 64

__global__ __launch_bounds__(256) void gemm_kernel(
    const ushort* __restrict__ A, const ushort* __restrict__ Bt,
    ushort* __restrict__ C, int M, int K)
{
    __shared__ __align__(16) char As[2][BM * BK * 2];   // 2 x 16KB
    __shared__ __align__(16) char Bs[2][BN * BK * 2];

    int t = threadIdx.x;
    int w = t >> 6, lane = t & 63;
    int bm = blockIdx.x * BM, bn = blockIdx.y * BN;
    int wr = (w >> 1) * 64, wc = (w & 1) * 64;

    floatx4 acc[4][4] = {};

    int l8 = lane >> 3;
    int cb = ((lane & 7) << 4) ^ ((l8 & 7) << 4);  // pre-swizzled source byte
    int rsw = (lane & 7) << 4;                     // read-side swizzle
    int nt = K / BK;

    auto stage = [&](int buf, int k0) {
#pragma unroll
        for (int c = 0; c < 4; c++) {
            int q = w * 4 + c;
            int row = q * 8 + l8;
            int ar = bm + row; if (ar > M - 1) ar = M - 1;
            const char* src = (const char*)A + ((size_t)ar * K + k0) * 2 + cb;
            __builtin_amdgcn_global_load_lds(
                (const __attribute__((address_space(1))) void*)src,
                (__attribute__((address_space(3))) void*)&As[buf][q * 1024], 16, 0, 0);
            int br = bn + row;
            const char* srcb = (const char*)Bt + ((size_t)br * K + k0) * 2 + cb;
            __builtin_amdgcn_global_load_lds(
                (const __attribute__((address_space(1))) void*)srcb,
                (__attribute__((address_space(3))) void*)&Bs[buf][q * 1024], 16, 0, 0);
        }
    };

    stage(0, 0);                                    // 8 loads in flight
    for (int tt = 0; tt < nt; tt++) {
        int cur = tt & 1;
        // protect buf cur^1 (read by compute of iter tt-1) before restaging it
        __builtin_amdgcn_s_barrier();
        if (tt + 1 < nt) {
            stage(cur ^ 1, (tt + 1) * BK);          // 8 more in flight
            asm volatile("s_waitcnt vmcnt(8)" ::: "memory");   // wait own cur-tile loads
        } else {
            asm volatile("s_waitcnt vmcnt(0)" ::: "memory");
        }
        __builtin_amdgcn_sched_barrier(0);
        __builtin_amdgcn_s_barrier();               // all waves' cur-tile loads visible
        __builtin_amdgcn_sched_barrier(0);

        const char* asb = As[cur];
        const char* bsb = Bs[cur];
#pragma unroll
        for (int ks = 0; ks < 2; ks++) {
            int kb = ks * 64 + ((lane >> 4) << 4);
            short8 a[4], b[4];
#pragma unroll
            for (int m = 0; m < 4; m++) {
                int row = wr + m * 16 + (lane & 15);
                a[m] = *(const short8*)&asb[row * 128 + (kb ^ rsw)];
            }
#pragma unroll
            for (int n = 0; n < 4; n++) {
                int row = wc + n * 16 + (lane & 15);
                b[n] = *(const short8*)&bsb[row * 128 + (kb ^ rsw)];
            }
#pragma unroll
            for (int m = 0; m < 4; m++)
#pragma unroll
                for (int n = 0; n < 4; n++)
                    acc[m][n] = __builtin_amdgcn_mfma_f32_16x16x32_bf16(a[m], b[n], acc[m][n], 0, 0, 0);
        }
    }

    int cl = lane & 15, rh = lane >> 4;
#pragma unroll
    for (int m = 0; m < 4; m++) {
#pragma unroll
        for (int r = 0; r < 4; r++) {
            int row = bm + wr + m * 16 + rh * 4 + r;
            if (row < M) {
                size_t base = (size_t)row * HID + bn + wc;
#pragma unroll
                for (int n = 0; n < 4; n++)
                    C[base + n * 16 + cl] = f2bf(acc[m][n][r]);
            }
        }
    }
}

// ---------------- attention scores s_src/s_dst [N,8] ----------------
__global__ void score_kernel(const ushort* __restrict__ hb,
                             const float* __restrict__ asrc,
                             const float* __restrict__ adst,
                             float* __restrict__ ssrc, float* __restrict__ sdst) {
    int idx = blockIdx.x * 256 + threadIdx.x;
    if (idx >= N_NODES * HEADS) return;
    int n = idx >> 3, h = idx & 7;
    const ushort* hp = &hb[(size_t)n * HID + h * 32];
    const float* ap = &asrc[h * 32];
    const float* dp = &adst[h * 32];
    float s1 = 0.f, s2 = 0.f;
#pragma unroll
    for (int j = 0; j < 32; j++) {
        float v = bf2f(hp[j]);
        s1 += v * ap[j];
        s2 += v * dp[j];
    }
    ssrc[idx] = s1;
    sdst[idx] = s2;
}

// ---------------- aggregation: one wave per node, 2 edge slots x 32 channel-lanes ----------
// no max-subtraction: |alpha| <~ 10 here, exp(alpha) safe in fp32, e/sum(e) identical.
// residual read + output write are bf16, in-place on the same buffer (per-node RMW, race-free)
__global__ __launch_bounds__(256) void agg_kernel(
    const ushort* __restrict__ hb, const float* __restrict__ ssrc,
    const float* __restrict__ sdst, const int* __restrict__ rowptr,
    const int* __restrict__ esrc, const float* __restrict__ bias,
    const float* __restrict__ gam, const float* __restrict__ bet,
    const float* __restrict__ bmean, const float* __restrict__ bvar,
    const ushort* __restrict__ residb, ushort* __restrict__ outb) {
    int wid = threadIdx.x >> 6;
    int lane = threadIdx.x & 63;
    int n = blockIdx.x * 4 + wid;
    if (n >= N_NODES) return;
    int start = rowptr[n], end = rowptr[n + 1];
    int slot = lane >> 5;        // which edge of a pair
    int cl = lane & 31;          // channel-lane: 8 channels each
    int c0 = cl * 8;
    int head = cl >> 2;          // c0/32
    float sdh = sdst[(size_t)n * 8 + head];

    float z = 0.f;
    float acc[8] = {};
    int i = start + slot;
    for (; i + 6 < end; i += 8) {
        int s0 = esrc[i], s1 = esrc[i + 2], s2 = esrc[i + 4], s3 = esrc[i + 6];
        float a0 = ssrc[(size_t)s0 * 8 + head] + sdh;
        float a1 = ssrc[(size_t)s1 * 8 + head] + sdh;
        float a2 = ssrc[(size_t)s2 * 8 + head] + sdh;
        float a3 = ssrc[(size_t)s3 * 8 + head] + sdh;
        ushort8v h0 = *(const ushort8v*)&hb[(size_t)s0 * HID + c0];
        ushort8v h1 = *(const ushort8v*)&hb[(size_t)s1 * HID + c0];
        ushort8v h2 = *(const ushort8v*)&hb[(size_t)s2 * HID + c0];
        ushort8v h3 = *(const ushort8v*)&hb[(size_t)s3 * HID + c0];
        a0 = (a0 >= 0.f) ? a0 : NEG_SLOPE * a0;
        a1 = (a1 >= 0.f) ? a1 : NEG_SLOPE * a1;
        a2 = (a2 >= 0.f) ? a2 : NEG_SLOPE * a2;
        a3 = (a3 >= 0.f) ? a3 : NEG_SLOPE * a3;
        float e0 = __expf(a0), e1 = __expf(a1), e2 = __expf(a2), e3 = __expf(a3);
        z += (e0 + e1) + (e2 + e3);
#pragma unroll
        for (int j = 0; j < 8; j++)
            acc[j] += (e0 * bf2f(h0[j]) + e1 * bf2f(h1[j])) +
                      (e2 * bf2f(h2[j]) + e3 * bf2f(h3[j]));
    }
    for (; i < end; i += 2) {
        int s = esrc[i];
        float a = ssrc[(size_t)s * 8 + head] + sdh;
        a = (a >= 0.f) ? a : NEG_SLOPE * a;
        float e = __expf(a);
        ushort8v hv = *(const ushort8v*)&hb[(size_t)s * HID + c0];
        z += e;
#pragma unroll
        for (int j = 0; j < 8; j++)
            acc[j] += e * bf2f(hv[j]);
    }
    // combine the two edge slots
    z += __shfl_xor(z, 32, 64);
#pragma unroll
    for (int j = 0; j < 8; j++)
        acc[j] += __shfl_xor(acc[j], 32, 64);

    if (lane < 32) {
        float inv = 1.f / (z + 1e-16f);
        float4 bv0 = *(const float4*)&bias[c0],   bv1 = *(const float4*)&bias[c0 + 4];
        float4 gv0 = *(const float4*)&gam[c0],    gv1 = *(const float4*)&gam[c0 + 4];
        float4 be0 = *(const float4*)&bet[c0],    be1 = *(const float4*)&bet[c0 + 4];
        float4 mv0 = *(const float4*)&bmean[c0],  mv1 = *(const float4*)&bmean[c0 + 4];
        float4 vv0 = *(const float4*)&bvar[c0],   vv1 = *(const float4*)&bvar[c0 + 4];
        float bs[8] = {bv0.x, bv0.y, bv0.z, bv0.w, bv1.x, bv1.y, bv1.z, bv1.w};
        float gs[8] = {gv0.x, gv0.y, gv0.z, gv0.w, gv1.x, gv1.y, gv1.z, gv1.w};
        float bes[8] = {be0.x, be0.y, be0.z, be0.w, be1.x, be1.y, be1.z, be1.w};
        float ms[8] = {mv0.x, mv0.y, mv0.z, mv0.w, mv1.x, mv1.y, mv1.z, mv1.w};
        float vs[8] = {vv0.x, vv0.y, vv0.z, vv0.w, vv1.x, vv1.y, vv1.z, vv1.w};
        float rs[8] = {};
        if (residb) {
            ushort8v rv = *(const ushort8v*)&residb[(size_t)n * HID + c0];
#pragma unroll
            for (int j = 0; j < 8; j++) rs[j] = bf2f(rv[j]);
        }
        ushort8v ob;
#pragma unroll
        for (int j = 0; j < 8; j++) {
            float val = acc[j] * inv + bs[j];
            val = (val - ms[j]) * rsqrtf(vs[j] + BN_EPS) * gs[j] + bes[j];
            val += rs[j];
            val = (val > 0.f) ? val : expm1f(val);   // ELU
            ob[j] = f2bf(val);
        }
        *(ushort8v*)&outb[(size_t)n * HID + c0] = ob;
    }
}

// ---------------- fused pooling + output heads ----------------
__global__ void poolhead_kernel(const ushort* __restrict__ hbf, const int* __restrict__ gstart,
                                const float* __restrict__ ow0, const float* __restrict__ ob0,
                                const float* __restrict__ ow1, const float* __restrict__ ob1,
                                float* __restrict__ out) {
    int g = blockIdx.x;
    int t = threadIdx.x;          // channel
    int s = gstart[g], e = gstart[g + 1];
    float sum = 0.f, mx = -INFINITY;
    for (int n = s; n < e; n++) {
        float v = bf2f(hbf[(size_t)n * HID + t]);
        sum += v;
        mx = fmaxf(mx, v);
    }
    int cnt = e - s;
    float mean = sum / fmaxf((float)cnt, 1.f);
    if (cnt == 0) mx = 0.f;

    float a0[3], a1[3];
#pragma unroll
    for (int j = 0; j < 3; j++) {
        a0[j] = mean * ow0[t * 3 + j] + sum * ow0[(256 + t) * 3 + j] + mx * ow0[(512 + t) * 3 + j];
        a1[j] = mean * ow1[t * 3 + j] + sum * ow1[(256 + t) * 3 + j] + mx * ow1[(512 + t) * 3 + j];
    }
    __shared__ float sd[6][256];
#pragma unroll
    for (int j = 0; j < 3; j++) { sd[j][t] = a0[j]; sd[3 + j][t] = a1[j]; }
    __syncthreads();
    for (int off = 128; off; off >>= 1) {
        if (t < off) {
#pragma unroll
            for (int j = 0; j < 6; j++) sd[j][t] += sd[j][t + off];
        }
        __syncthreads();
    }
    if (t < 3) {
        out[g * 3 + t] = sd[t][0] + ob0[t];
        out[1536 + g * 3 + t] = sd[3 + t][0] + ob1[t];
    }
}

// ---------------- launch ----------------
extern "C" void kernel_launch(void* const* d_in, const int* in_sizes, int n_in,
                              void* d_out, int out_size, void* d_ws, size_t ws_size,
                              hipStream_t stream) {
    const float* x     = (const float*)d_in[0];
    const int*   ei    = (const int*)d_in[1];
    const int*   batch = (const int*)d_in[2];
    const float* W[3]  = {(const float*)d_in[3], (const float*)d_in[11], (const float*)d_in[19]};
    const float* AS[3] = {(const float*)d_in[4], (const float*)d_in[12], (const float*)d_in[20]};
    const float* AD[3] = {(const float*)d_in[5], (const float*)d_in[13], (const float*)d_in[21]};
    const float* B[3]  = {(const float*)d_in[6], (const float*)d_in[14], (const float*)d_in[22]};
    const float* GM[3] = {(const float*)d_in[7], (const float*)d_in[15], (const float*)d_in[23]};
    const float* BE[3] = {(const float*)d_in[8], (const float*)d_in[16], (const float*)d_in[24]};
    const float* M[3]  = {(const float*)d_in[9], (const float*)d_in[17], (const float*)d_in[25]};
    const float* V[3]  = {(const float*)d_in[10], (const float*)d_in[18], (const float*)d_in[26]};
    const float* ow0 = (const float*)d_in[27];
    const float* ob0 = (const float*)d_in[28];
    const float* ow1 = (const float*)d_in[29];
    const float* ob1 = (const float*)d_in[30];
    float* out = (float*)d_out;

    // workspace carve
    char* p = (char*)d_ws;
    int* rowptr = (int*)p;  p += (size_t)(N_NODES + 1) * 4;
    int* fill   = (int*)p;  p += (size_t)N_NODES * 4;
    int* esrc   = (int*)p;  p += (size_t)EP * 4;
    int* gstart = (int*)p;  p += (size_t)(G_GRAPHS + 1) * 4;
    int* bsum   = (int*)p;  p += (size_t)(NB_SCAN + 1) * 4;
    p = (char*)(((uintptr_t)p + 255) & ~(uintptr_t)255);
    ushort* hb    = (ushort*)p; p += (size_t)N_NODES * HID * 2;      // GEMM out (bf16)
    ushort* curhb = (ushort*)p; p += (size_t)N_NODES * HID * 2;      // layer out (bf16)
    ushort* xb    = (ushort*)p; p += (size_t)N_NODES * 128 * 2;      // x bf16
    ushort* Wt0   = (ushort*)p; p += (size_t)256 * 128 * 2;
    ushort* Wt1   = (ushort*)p; p += (size_t)256 * 256 * 2;
    ushort* Wt2   = (ushort*)p; p += (size_t)256 * 256 * 2;
    float* ssrc   = (float*)p;  p += (size_t)N_NODES * HEADS * 4;
    float* sdst   = (float*)p;  p += (size_t)N_NODES * HEADS * 4;

    // CSR build
    hipMemsetAsync(fill, 0, (size_t)N_NODES * 4, stream);
    hist_kernel<<<(EP + 255) / 256, 256, 0, stream>>>(ei, fill);
    scan1_kernel<<<NB_SCAN, 1024, 0, stream>>>(fill, rowptr, bsum);
    scan3_kernel<<<NB_SCAN, 1024, 0, stream>>>(rowptr, fill, bsum);
    scatter_kernel<<<(EP + 255) / 256, 256, 0, stream>>>(ei, fill, esrc);
    gstart_kernel<<<(G_GRAPHS + 64) / 64, 64, 0, stream>>>(batch, gstart);

    // bf16 conversions
    cvt_kernel<<<(N_NODES * 128 / 4 + 255) / 256, 256, 0, stream>>>(x, xb, N_NODES * 128 / 4);
    {
        dim3 wgrid(256, 3);
        wt_all_kernel<<<wgrid, 256, 0, stream>>>(W[0], W[1], W[2], Wt0, Wt1, Wt2);
    }
    const ushort* Wt[3] = {Wt0, Wt1, Wt2};

    dim3 ggrid((N_NODES + BM - 1) / BM, HID / BN);
    int sgrid = (N_NODES * HEADS + 255) / 256;
    int agrid = (N_NODES + 3) / 4;

    // layer 1 (input xb, K=128, no residual)
    gemm_kernel<<<ggrid, 256, 0, stream>>>(xb, Wt[0], hb, N_NODES, 128);
    score_kernel<<<sgrid, 256, 0, stream>>>(hb, AS[0], AD[0], ssrc, sdst);
    agg_kernel<<<agrid, 256, 0, stream>>>(hb, ssrc, sdst, rowptr, esrc,
                                          B[0], GM[0], BE[0], M[0], V[0],
                                          nullptr, curhb);
    // layers 2,3: residual read + output write both bf16, in place on curhb
    for (int l = 1; l < 3; l++) {
        gemm_kernel<<<ggrid, 256, 0, stream>>>(curhb, Wt[l], hb, N_NODES, 256);
        score_kernel<<<sgrid, 256, 0, stream>>>(hb, AS[l], AD[l], ssrc, sdst);
        agg_kernel<<<agrid, 256, 0, stream>>>(hb, ssrc, sdst, rowptr, esrc,
                                              B[l], GM[l], BE[l], M[l], V[l],
                                              curhb, curhb);
    }

    // fused pooling + heads
    poolhead_kernel<<<G_GRAPHS, 256, 0, stream>>>(curhb, gstart, ow0, ob0, ow1, ob1, out);
}

// Round 6
// 561.417 us; speedup vs baseline: 1.9939x; 1.0681x over previous
//
#include <hip/hip_runtime.h>
#include <hip/hip_bf16.h>
#include <math.h>

#define N_NODES 50000
#define N_EDGES 800000
#define EP (N_EDGES + N_NODES)   // edges + self loops
#define G_GRAPHS 512
#define HID 256
#define HEADS 8
#define NEG_SLOPE 0.2f
#define BN_EPS 1e-5f
#define NB_SCAN ((N_NODES + 1023) / 1024)   // 49

typedef __attribute__((ext_vector_type(8))) short short8;
typedef __attribute__((ext_vector_type(8))) unsigned short ushort8v;
typedef __attribute__((ext_vector_type(4))) float floatx4;

__device__ __forceinline__ float bf2f(ushort u) {
    return __uint_as_float(((unsigned)u) << 16);
}
__device__ __forceinline__ ushort f2bf(float f) {
    unsigned u = __float_as_uint(f);
    u += 0x7fff + ((u >> 16) & 1);   // RNE
    return (ushort)(u >> 16);
}

// ---------------- CSR build ----------------

__global__ void hist_kernel(const int* __restrict__ ei, int* __restrict__ fill) {
    int e = blockIdx.x * 256 + threadIdx.x;
    if (e >= EP) return;
    int d = (e < N_EDGES) ? ei[N_EDGES + e] : (e - N_EDGES);
    atomicAdd(&fill[d], 1);
}

// block-level scan: rowptr[idx] = exclusive-within-block, bsum[b] = block total
__global__ void scan1_kernel(const int* __restrict__ fill, int* __restrict__ rowptr,
                             int* __restrict__ bsum) {
    __shared__ int sdata[1024];
    int tid = threadIdx.x;
    int idx = blockIdx.x * 1024 + tid;
    int v = (idx < N_NODES) ? fill[idx] : 0;
    sdata[tid] = v;
    __syncthreads();
    for (int off = 1; off < 1024; off <<= 1) {
        int x = (tid >= off) ? sdata[tid - off] : 0;
        __syncthreads();
        sdata[tid] += x;
        __syncthreads();
    }
    if (idx < N_NODES) rowptr[idx] = sdata[tid] - v;
    if (tid == 1023) bsum[blockIdx.x] = sdata[1023];
}

// adds block-prefix (computed locally by wave-scanning bsum) -> rowptr/fill global
__global__ void scan3_kernel(int* __restrict__ rowptr, int* __restrict__ fill,
                             const int* __restrict__ bsum) {
    __shared__ int soff[2];
    int tid = threadIdx.x;
    if (tid < 64) {
        int v = (tid < NB_SCAN) ? bsum[tid] : 0;
        int incl = v;
#pragma unroll
        for (int off = 1; off < 64; off <<= 1) {
            int x = __shfl_up(incl, off, 64);
            if (tid >= off) incl += x;
        }
        if (tid == blockIdx.x) soff[0] = incl - v;
        if (tid == NB_SCAN - 1) soff[1] = incl;
    }
    __syncthreads();
    int idx = blockIdx.x * 1024 + tid;
    if (idx < N_NODES) {
        int e = rowptr[idx] + soff[0];
        rowptr[idx] = e;
        fill[idx] = e;
    }
    if (idx == N_NODES) rowptr[N_NODES] = soff[1];
}

__global__ void scatter_kernel(const int* __restrict__ ei, int* __restrict__ fill,
                               int* __restrict__ esrc) {
    int e = blockIdx.x * 256 + threadIdx.x;
    if (e >= EP) return;
    int s, d;
    if (e < N_EDGES) { s = ei[e]; d = ei[N_EDGES + e]; }
    else             { s = d = e - N_EDGES; }
    int pos = atomicAdd(&fill[d], 1);
    esrc[pos] = s;
}

__global__ void gstart_kernel(const int* __restrict__ batch, int* __restrict__ gstart) {
    int g = blockIdx.x * 64 + threadIdx.x;
    if (g > G_GRAPHS) return;
    int lo = 0, hi = N_NODES;
    while (lo < hi) { int mid = (lo + hi) >> 1; if (batch[mid] < g) lo = mid + 1; else hi = mid; }
    gstart[g] = lo;
}

// ---------------- conversions ----------------

__global__ void cvt_kernel(const float* __restrict__ in, ushort* __restrict__ out, int n4) {
    int i = blockIdx.x * 256 + threadIdx.x;
    if (i >= n4) return;
    float4 v = *(const float4*)&in[(size_t)i * 4];
    ushort4 o = {f2bf(v.x), f2bf(v.y), f2bf(v.z), f2bf(v.w)};
    *(ushort4*)&out[(size_t)i * 4] = o;
}

// Wt[c][k] = bf16(W[k][c]) for all three layers; gridDim=(256,3)
__global__ void wt_all_kernel(const float* __restrict__ W0, const float* __restrict__ W1,
                              const float* __restrict__ W2, ushort* __restrict__ Wt0,
                              ushort* __restrict__ Wt1, ushort* __restrict__ Wt2) {
    int m = blockIdx.y;
    const float* W = (m == 0) ? W0 : (m == 1) ? W1 : W2;
    ushort* Wt = (m == 0) ? Wt0 : (m == 1) ? Wt1 : Wt2;
    int K = (m == 0) ? 128 : 256;
    int c = blockIdx.x, k = threadIdx.x;
    if (k < K) Wt[(size_t)c * K + k] = f2bf(W[(size_t)k * HID + c]);
}

// ---------------- MFMA GEMM: C[M,256] = A[M,K] @ Wt[256,K]^T (bf16 in/out) ----------------
// 128x128 tile, BK=64, double-buffered LDS, counted vmcnt (loads fly across barriers)
#define BM 128
#define BN 128
#define BK 64

__global__ __launch_bounds__(256) void gemm_kernel(
    const ushort* __restrict__ A, const ushort* __restrict__ Bt,
    ushort* __restrict__ C, int M, int K)
{
    __shared__ __align__(16) char As[2][BM * BK * 2];   // 2 x 16KB
    __shared__ __align__(16) char Bs[2][BN * BK * 2];

    int t = threadIdx.x;
    int w = t >> 6, lane = t & 63;
    int bm = blockIdx.x * BM, bn = blockIdx.y * BN;
    int wr = (w >> 1) * 64, wc = (w & 1) * 64;

    floatx4 acc[4][4] = {};

    int l8 = lane >> 3;
    int cb = ((lane & 7) << 4) ^ ((l8 & 7) << 4);  // pre-swizzled source byte
    int rsw = (lane & 7) << 4;                     // read-side swizzle
    int nt = K / BK;

    auto stage = [&](int buf, int k0) {
#pragma unroll
        for (int c = 0; c < 4; c++) {
            int q = w * 4 + c;
            int row = q * 8 + l8;
            int ar = bm + row; if (ar > M - 1) ar = M - 1;
            const char* src = (const char*)A + ((size_t)ar * K + k0) * 2 + cb;
            __builtin_amdgcn_global_load_lds(
                (const __attribute__((address_space(1))) void*)src,
                (__attribute__((address_space(3))) void*)&As[buf][q * 1024], 16, 0, 0);
            int br = bn + row;
            const char* srcb = (const char*)Bt + ((size_t)br * K + k0) * 2 + cb;
            __builtin_amdgcn_global_load_lds(
                (const __attribute__((address_space(1))) void*)srcb,
                (__attribute__((address_space(3))) void*)&Bs[buf][q * 1024], 16, 0, 0);
        }
    };

    stage(0, 0);                                    // 8 loads in flight
    for (int tt = 0; tt < nt; tt++) {
        int cur = tt & 1;
        // protect buf cur^1 (read by compute of iter tt-1) before restaging it
        __builtin_amdgcn_s_barrier();
        if (tt + 1 < nt) {
            stage(cur ^ 1, (tt + 1) * BK);          // 8 more in flight
            asm volatile("s_waitcnt vmcnt(8)" ::: "memory");   // wait own cur-tile loads
        } else {
            asm volatile("s_waitcnt vmcnt(0)" ::: "memory");
        }
        __builtin_amdgcn_sched_barrier(0);
        __builtin_amdgcn_s_barrier();               // all waves' cur-tile loads visible
        __builtin_amdgcn_sched_barrier(0);

        const char* asb = As[cur];
        const char* bsb = Bs[cur];
#pragma unroll
        for (int ks = 0; ks < 2; ks++) {
            int kb = ks * 64 + ((lane >> 4) << 4);
            short8 a[4], b[4];
#pragma unroll
            for (int m = 0; m < 4; m++) {
                int row = wr + m * 16 + (lane & 15);
                a[m] = *(const short8*)&asb[row * 128 + (kb ^ rsw)];
            }
#pragma unroll
            for (int n = 0; n < 4; n++) {
                int row = wc + n * 16 + (lane & 15);
                b[n] = *(const short8*)&bsb[row * 128 + (kb ^ rsw)];
            }
#pragma unroll
            for (int m = 0; m < 4; m++)
#pragma unroll
                for (int n = 0; n < 4; n++)
                    acc[m][n] = __builtin_amdgcn_mfma_f32_16x16x32_bf16(a[m], b[n], acc[m][n], 0, 0, 0);
        }
    }

    int cl = lane & 15, rh = lane >> 4;
#pragma unroll
    for (int m = 0; m < 4; m++) {
#pragma unroll
        for (int r = 0; r < 4; r++) {
            int row = bm + wr + m * 16 + rh * 4 + r;
            if (row < M) {
                size_t base = (size_t)row * HID + bn + wc;
#pragma unroll
                for (int n = 0; n < 4; n++)
                    C[base + n * 16 + cl] = f2bf(acc[m][n][r]);
            }
        }
    }
}

// ---------------- attention scores: wave = 2 nodes, lane = 16B chunk ----------------
// lane cl (0..31) of node n loads h[n][cl*8 .. cl*8+7] (one short8, coalesced),
// dots with asrc/adst (flat [256]), 4-lane shfl reduce -> per-head scores.
__global__ __launch_bounds__(256) void score_kernel(
    const ushort* __restrict__ hb, const float* __restrict__ asrc,
    const float* __restrict__ adst, float* __restrict__ ssrc,
    float* __restrict__ sdst) {
    int t = threadIdx.x;
    int lane = t & 63;
    int wid = t >> 6;
    unsigned n = (unsigned)(blockIdx.x * 8 + wid * 2 + (lane >> 5));
    unsigned cl = lane & 31;
    unsigned c0 = cl * 8u;
    ushort8v hv = *(const ushort8v*)&hb[n * 256u + c0];
    float s1 = 0.f, s2 = 0.f;
#pragma unroll
    for (int j = 0; j < 8; j++) {
        float v = bf2f(hv[j]);
        s1 += v * asrc[c0 + j];
        s2 += v * adst[c0 + j];
    }
    s1 += __shfl_xor(s1, 1, 64); s2 += __shfl_xor(s2, 1, 64);
    s1 += __shfl_xor(s1, 2, 64); s2 += __shfl_xor(s2, 2, 64);
    if ((cl & 3) == 0) {
        unsigned h = cl >> 2;
        ssrc[n * 8u + h] = s1;
        sdst[n * 8u + h] = s2;
    }
}

// ---------------- aggregation: one wave per node, 2 edge slots x 32 channel-lanes ----------
// no max-subtraction: |alpha| <~ 10 here, exp(alpha) safe in fp32, e/sum(e) identical.
// all gathers use unsigned 32-bit offsets -> global_load saddr form (cheap addressing).
__global__ __launch_bounds__(256) void agg_kernel(
    const ushort* __restrict__ hb, const float* __restrict__ ssrc,
    const float* __restrict__ sdst, const int* __restrict__ rowptr,
    const int* __restrict__ esrc, const float* __restrict__ bias,
    const float* __restrict__ gam, const float* __restrict__ bet,
    const float* __restrict__ bmean, const float* __restrict__ bvar,
    const ushort* __restrict__ residb, ushort* __restrict__ outb) {
    int wid = threadIdx.x >> 6;
    int lane = threadIdx.x & 63;
    int n = blockIdx.x * 4 + wid;
    if (n >= N_NODES) return;
    int start = rowptr[n], end = rowptr[n + 1];
    int slot = lane >> 5;        // which edge of a pair
    unsigned cl = lane & 31;     // channel-lane: 8 channels each
    unsigned c0 = cl * 8u;
    unsigned head = cl >> 2;     // c0/32
    float sdh = sdst[(unsigned)n * 8u + head];

    float z = 0.f;
    float acc[8] = {};
    int i = start + slot;
    for (; i + 6 < end; i += 8) {
        unsigned s0 = (unsigned)esrc[i], s1 = (unsigned)esrc[i + 2];
        unsigned s2 = (unsigned)esrc[i + 4], s3 = (unsigned)esrc[i + 6];
        float a0 = ssrc[s0 * 8u + head] + sdh;
        float a1 = ssrc[s1 * 8u + head] + sdh;
        float a2 = ssrc[s2 * 8u + head] + sdh;
        float a3 = ssrc[s3 * 8u + head] + sdh;
        ushort8v h0 = *(const ushort8v*)&hb[s0 * 256u + c0];
        ushort8v h1 = *(const ushort8v*)&hb[s1 * 256u + c0];
        ushort8v h2 = *(const ushort8v*)&hb[s2 * 256u + c0];
        ushort8v h3 = *(const ushort8v*)&hb[s3 * 256u + c0];
        a0 = fmaxf(a0, NEG_SLOPE * a0);
        a1 = fmaxf(a1, NEG_SLOPE * a1);
        a2 = fmaxf(a2, NEG_SLOPE * a2);
        a3 = fmaxf(a3, NEG_SLOPE * a3);
        float e0 = __expf(a0), e1 = __expf(a1), e2 = __expf(a2), e3 = __expf(a3);
        z += (e0 + e1) + (e2 + e3);
#pragma unroll
        for (int j = 0; j < 8; j++)
            acc[j] += (e0 * bf2f(h0[j]) + e1 * bf2f(h1[j])) +
                      (e2 * bf2f(h2[j]) + e3 * bf2f(h3[j]));
    }
    for (; i < end; i += 2) {
        unsigned s = (unsigned)esrc[i];
        float a = ssrc[s * 8u + head] + sdh;
        a = fmaxf(a, NEG_SLOPE * a);
        float e = __expf(a);
        ushort8v hv = *(const ushort8v*)&hb[s * 256u + c0];
        z += e;
#pragma unroll
        for (int j = 0; j < 8; j++)
            acc[j] += e * bf2f(hv[j]);
    }
    // combine the two edge slots
    z += __shfl_xor(z, 32, 64);
#pragma unroll
    for (int j = 0; j < 8; j++)
        acc[j] += __shfl_xor(acc[j], 32, 64);

    if (lane < 32) {
        float inv = 1.f / (z + 1e-16f);
        float4 bv0 = *(const float4*)&bias[c0],   bv1 = *(const float4*)&bias[c0 + 4];
        float4 gv0 = *(const float4*)&gam[c0],    gv1 = *(const float4*)&gam[c0 + 4];
        float4 be0 = *(const float4*)&bet[c0],    be1 = *(const float4*)&bet[c0 + 4];
        float4 mv0 = *(const float4*)&bmean[c0],  mv1 = *(const float4*)&bmean[c0 + 4];
        float4 vv0 = *(const float4*)&bvar[c0],   vv1 = *(const float4*)&bvar[c0 + 4];
        float bs[8] = {bv0.x, bv0.y, bv0.z, bv0.w, bv1.x, bv1.y, bv1.z, bv1.w};
        float gs[8] = {gv0.x, gv0.y, gv0.z, gv0.w, gv1.x, gv1.y, gv1.z, gv1.w};
        float bes[8] = {be0.x, be0.y, be0.z, be0.w, be1.x, be1.y, be1.z, be1.w};
        float ms[8] = {mv0.x, mv0.y, mv0.z, mv0.w, mv1.x, mv1.y, mv1.z, mv1.w};
        float vs[8] = {vv0.x, vv0.y, vv0.z, vv0.w, vv1.x, vv1.y, vv1.z, vv1.w};
        float rs[8] = {};
        if (residb) {
            ushort8v rv = *(const ushort8v*)&residb[(unsigned)n * 256u + c0];
#pragma unroll
            for (int j = 0; j < 8; j++) rs[j] = bf2f(rv[j]);
        }
        ushort8v ob;
#pragma unroll
        for (int j = 0; j < 8; j++) {
            float val = acc[j] * inv + bs[j];
            val = (val - ms[j]) * rsqrtf(vs[j] + BN_EPS) * gs[j] + bes[j];
            val += rs[j];
            val = (val > 0.f) ? val : expm1f(val);   // ELU
            ob[j] = f2bf(val);
        }
        *(ushort8v*)&outb[(unsigned)n * 256u + c0] = ob;
    }
}

// ---------------- fused pooling + output heads ----------------
__global__ void poolhead_kernel(const ushort* __restrict__ hbf, const int* __restrict__ gstart,
                                const float* __restrict__ ow0, const float* __restrict__ ob0,
                                const float* __restrict__ ow1, const float* __restrict__ ob1,
                                float* __restrict__ out) {
    int g = blockIdx.x;
    int t = threadIdx.x;          // channel
    int s = gstart[g], e = gstart[g + 1];
    float sum = 0.f, mx = -INFINITY;
    for (int n = s; n < e; n++) {
        float v = bf2f(hbf[(unsigned)n * 256u + t]);
        sum += v;
        mx = fmaxf(mx, v);
    }
    int cnt = e - s;
    float mean = sum / fmaxf((float)cnt, 1.f);
    if (cnt == 0) mx = 0.f;

    float a0[3], a1[3];
#pragma unroll
    for (int j = 0; j < 3; j++) {
        a0[j] = mean * ow0[t * 3 + j] + sum * ow0[(256 + t) * 3 + j] + mx * ow0[(512 + t) * 3 + j];
        a1[j] = mean * ow1[t * 3 + j] + sum * ow1[(256 + t) * 3 + j] + mx * ow1[(512 + t) * 3 + j];
    }
    __shared__ float sd[6][256];
#pragma unroll
    for (int j = 0; j < 3; j++) { sd[j][t] = a0[j]; sd[3 + j][t] = a1[j]; }
    __syncthreads();
    for (int off = 128; off; off >>= 1) {
        if (t < off) {
#pragma unroll
            for (int j = 0; j < 6; j++) sd[j][t] += sd[j][t + off];
        }
        __syncthreads();
    }
    if (t < 3) {
        out[g * 3 + t] = sd[t][0] + ob0[t];
        out[1536 + g * 3 + t] = sd[3 + t][0] + ob1[t];
    }
}

// ---------------- launch ----------------
extern "C" void kernel_launch(void* const* d_in, const int* in_sizes, int n_in,
                              void* d_out, int out_size, void* d_ws, size_t ws_size,
                              hipStream_t stream) {
    const float* x     = (const float*)d_in[0];
    const int*   ei    = (const int*)d_in[1];
    const int*   batch = (const int*)d_in[2];
    const float* W[3]  = {(const float*)d_in[3], (const float*)d_in[11], (const float*)d_in[19]};
    const float* AS[3] = {(const float*)d_in[4], (const float*)d_in[12], (const float*)d_in[20]};
    const float* AD[3] = {(const float*)d_in[5], (const float*)d_in[13], (const float*)d_in[21]};
    const float* B[3]  = {(const float*)d_in[6], (const float*)d_in[14], (const float*)d_in[22]};
    const float* GM[3] = {(const float*)d_in[7], (const float*)d_in[15], (const float*)d_in[23]};
    const float* BE[3] = {(const float*)d_in[8], (const float*)d_in[16], (const float*)d_in[24]};
    const float* M[3]  = {(const float*)d_in[9], (const float*)d_in[17], (const float*)d_in[25]};
    const float* V[3]  = {(const float*)d_in[10], (const float*)d_in[18], (const float*)d_in[26]};
    const float* ow0 = (const float*)d_in[27];
    const float* ob0 = (const float*)d_in[28];
    const float* ow1 = (const float*)d_in[29];
    const float* ob1 = (const float*)d_in[30];
    float* out = (float*)d_out;

    // workspace carve
    char* p = (char*)d_ws;
    int* rowptr = (int*)p;  p += (size_t)(N_NODES + 1) * 4;
    int* fill   = (int*)p;  p += (size_t)N_NODES * 4;
    int* esrc   = (int*)p;  p += (size_t)EP * 4;
    int* gstart = (int*)p;  p += (size_t)(G_GRAPHS + 1) * 4;
    int* bsum   = (int*)p;  p += (size_t)(NB_SCAN + 1) * 4;
    p = (char*)(((uintptr_t)p + 255) & ~(uintptr_t)255);
    ushort* hb    = (ushort*)p; p += (size_t)N_NODES * HID * 2;      // GEMM out (bf16)
    ushort* curhb = (ushort*)p; p += (size_t)N_NODES * HID * 2;      // layer out (bf16)
    ushort* xb    = (ushort*)p; p += (size_t)N_NODES * 128 * 2;      // x bf16
    ushort* Wt0   = (ushort*)p; p += (size_t)256 * 128 * 2;
    ushort* Wt1   = (ushort*)p; p += (size_t)256 * 256 * 2;
    ushort* Wt2   = (ushort*)p; p += (size_t)256 * 256 * 2;
    float* ssrc   = (float*)p;  p += (size_t)N_NODES * HEADS * 4;
    float* sdst   = (float*)p;  p += (size_t)N_NODES * HEADS * 4;

    // CSR build
    hipMemsetAsync(fill, 0, (size_t)N_NODES * 4, stream);
    hist_kernel<<<(EP + 255) / 256, 256, 0, stream>>>(ei, fill);
    scan1_kernel<<<NB_SCAN, 1024, 0, stream>>>(fill, rowptr, bsum);
    scan3_kernel<<<NB_SCAN, 1024, 0, stream>>>(rowptr, fill, bsum);
    scatter_kernel<<<(EP + 255) / 256, 256, 0, stream>>>(ei, fill, esrc);
    gstart_kernel<<<(G_GRAPHS + 64) / 64, 64, 0, stream>>>(batch, gstart);

    // bf16 conversions
    cvt_kernel<<<(N_NODES * 128 / 4 + 255) / 256, 256, 0, stream>>>(x, xb, N_NODES * 128 / 4);
    {
        dim3 wgrid(256, 3);
        wt_all_kernel<<<wgrid, 256, 0, stream>>>(W[0], W[1], W[2], Wt0, Wt1, Wt2);
    }
    const ushort* Wt[3] = {Wt0, Wt1, Wt2};

    dim3 ggrid((N_NODES + BM - 1) / BM, HID / BN);
    int sgrid = N_NODES / 8;            // 6250 blocks, 8 nodes per block
    int agrid = (N_NODES + 3) / 4;

    // layer 1 (input xb, K=128, no residual)
    gemm_kernel<<<ggrid, 256, 0, stream>>>(xb, Wt[0], hb, N_NODES, 128);
    score_kernel<<<sgrid, 256, 0, stream>>>(hb, AS[0], AD[0], ssrc, sdst);
    agg_kernel<<<agrid, 256, 0, stream>>>(hb, ssrc, sdst, rowptr, esrc,
                                          B[0], GM[0], BE[0], M[0], V[0],
                                          nullptr, curhb);
    // layers 2,3: residual read + output write both bf16, in place on curhb
    for (int l = 1; l < 3; l++) {
        gemm_kernel<<<ggrid, 256, 0, stream>>>(curhb, Wt[l], hb, N_NODES, 256);
        score_kernel<<<sgrid, 256, 0, stream>>>(hb, AS[l], AD[l], ssrc, sdst);
        agg_kernel<<<agrid, 256, 0, stream>>>(hb, ssrc, sdst, rowptr, esrc,
                                              B[l], GM[l], BE[l], M[l], V[l],
                                              curhb, curhb);
    }

    // fused pooling + heads
    poolhead_kernel<<<G_GRAPHS, 256, 0, stream>>>(curhb, gstart, ow0, ob0, ow1, ob1, out);
}